// Round 1
// baseline (995.204 us; speedup 1.0000x reference)
//
#include <hip/hip_runtime.h>
#include <math.h>

#define NN 20000
#define EE 320000
#define ETOT 340000   // EE + NN self-loops
#define NHEADS 8
#define HID 64
#define HCV 512       // NHEADS*HID
#define IND 128
#define OUTD 128
#define NEG_SLOPE 0.2f

// ---------------- CSR build ----------------

__global__ void zero_i32(int* p, int n) {
    int i = blockIdx.x * blockDim.x + threadIdx.x;
    if (i < n) p[i] = 0;
}

// count incoming edges per dst (edges + self loops)
__global__ void count_kernel(const int* __restrict__ ei, int* __restrict__ cnt) {
    int i = blockIdx.x * blockDim.x + threadIdx.x;
    if (i >= ETOT) return;
    int v = (i < EE) ? ei[EE + i] : (i - EE);
    atomicAdd(&cnt[v], 1);
}

// single-block exclusive scan of cnt[NN] -> row_ptr[NN+1]
__global__ void scan_kernel(const int* __restrict__ cnt, int* __restrict__ row_ptr) {
    __shared__ int tot[256];
    __shared__ int pre[256];
    int t = threadIdx.x;
    const int CH = (NN + 255) / 256;
    int base = t * CH;
    int s = 0;
    for (int i = 0; i < CH; i++) {
        int idx = base + i;
        if (idx < NN) s += cnt[idx];
    }
    tot[t] = s;
    __syncthreads();
    if (t == 0) {
        int run = 0;
        for (int j = 0; j < 256; j++) { pre[j] = run; run += tot[j]; }
        row_ptr[NN] = run;
    }
    __syncthreads();
    int run = pre[t];
    for (int i = 0; i < CH; i++) {
        int idx = base + i;
        if (idx < NN) { row_ptr[idx] = run; run += cnt[idx]; }
    }
}

__global__ void init_cursor(const int* __restrict__ row_ptr, int* __restrict__ cursor) {
    int i = blockIdx.x * blockDim.x + threadIdx.x;
    if (i < NN) cursor[i] = row_ptr[i];
}

__global__ void fill_kernel(const int* __restrict__ ei, int* __restrict__ cursor,
                            int* __restrict__ csr_src) {
    int i = blockIdx.x * blockDim.x + threadIdx.x;
    if (i >= ETOT) return;
    int u, v;
    if (i < EE) { u = ei[i]; v = ei[EE + i]; }
    else        { u = i - EE; v = i - EE; }
    int pos = atomicAdd(&cursor[v], 1);
    csr_src[pos] = u;
}

// ---------------- GEMM: C[M,Nc] = A[M,K] @ B[K,Nc], fp32 ----------------
// 64x64 tile, BK=16, 256 threads (16x16), 4x4 microtile per thread.
__global__ __launch_bounds__(256) void gemm64(const float* __restrict__ A,
                                              const float* __restrict__ B,
                                              float* __restrict__ C,
                                              int M, int K, int Nc) {
    __shared__ float As[16][68];   // [k][m], pad 68 keeps 16B alignment, 2-way bank alias only
    __shared__ float Bs[16][64];   // [k][n]
    int tid = threadIdx.x;
    int tx = tid & 15, ty = tid >> 4;
    int m0 = blockIdx.x * 64, n0 = blockIdx.y * 64;
    float acc[4][4] = {};
    for (int k0 = 0; k0 < K; k0 += 16) {
        // A tile: 64 rows x 16 k, transposed into As[k][m]
        {
            int j = tid & 15;       // k
            int i0 = tid >> 4;      // m base
            #pragma unroll
            for (int r = 0; r < 4; r++) {
                int i = i0 + r * 16;
                int m = m0 + i;
                As[j][i] = (m < M) ? A[(size_t)m * K + k0 + j] : 0.f;
            }
        }
        // B tile: 16 k rows x 64 n
        {
            int n = tid & 63;
            int kk0 = tid >> 6;
            #pragma unroll
            for (int r = 0; r < 4; r++) {
                int kk = kk0 + r * 4;
                Bs[kk][n] = B[(size_t)(k0 + kk) * Nc + n0 + n];
            }
        }
        __syncthreads();
        #pragma unroll
        for (int kk = 0; kk < 16; kk++) {
            float4 a4 = *(const float4*)&As[kk][ty * 4];
            float4 b4 = *(const float4*)&Bs[kk][tx * 4];
            float av[4] = {a4.x, a4.y, a4.z, a4.w};
            float bv[4] = {b4.x, b4.y, b4.z, b4.w};
            #pragma unroll
            for (int i = 0; i < 4; i++)
                #pragma unroll
                for (int j = 0; j < 4; j++)
                    acc[i][j] += av[i] * bv[j];
        }
        __syncthreads();
    }
    #pragma unroll
    for (int r = 0; r < 4; r++) {
        int m = m0 + ty * 4 + r;
        if (m < M) {
            float4 v = make_float4(acc[r][0], acc[r][1], acc[r][2], acc[r][3]);
            *(float4*)&C[(size_t)m * Nc + n0 + tx * 4] = v;
        }
    }
}

// ---------------- attention half-logits, layers 1/2 (8 heads x 64) ----------------
// one wave per (node, head); lane = channel
__global__ __launch_bounds__(256) void al_kernel(const float* __restrict__ h,
                                                 const float* __restrict__ a_src,
                                                 const float* __restrict__ a_dst,
                                                 float* __restrict__ als,
                                                 float* __restrict__ ald) {
    int lane = threadIdx.x & 63;
    int w = blockIdx.x * 4 + (threadIdx.x >> 6);
    int n = w >> 3, hd = w & 7;
    if (n >= NN) return;
    float v = h[(size_t)n * HCV + hd * HID + lane];
    float s = v * a_src[hd * HID + lane];
    float d = v * a_dst[hd * HID + lane];
    for (int off = 32; off > 0; off >>= 1) {
        s += __shfl_down(s, off);
        d += __shfl_down(d, off);
    }
    if (lane == 0) {
        als[n * NHEADS + hd] = s;
        ald[n * NHEADS + hd] = d;
    }
}

// layer 3: 1 head x 128 channels; one wave per node, 2 channels/lane
__global__ __launch_bounds__(256) void al3_kernel(const float* __restrict__ h,
                                                  const float* __restrict__ a_src,
                                                  const float* __restrict__ a_dst,
                                                  float* __restrict__ als,
                                                  float* __restrict__ ald) {
    int lane = threadIdx.x & 63;
    int n = blockIdx.x * 4 + (threadIdx.x >> 6);
    if (n >= NN) return;
    float v0 = h[(size_t)n * OUTD + lane];
    float v1 = h[(size_t)n * OUTD + 64 + lane];
    float s = v0 * a_src[lane] + v1 * a_src[64 + lane];
    float d = v0 * a_dst[lane] + v1 * a_dst[64 + lane];
    for (int off = 32; off > 0; off >>= 1) {
        s += __shfl_down(s, off);
        d += __shfl_down(d, off);
    }
    if (lane == 0) { als[n] = s; ald[n] = d; }
}

// ---------------- edge-softmax gather-aggregate, layers 1/2 ----------------
// one wave per (dst node, head); lane = channel; online softmax over incoming edges
__global__ __launch_bounds__(256) void agg_kernel(const float* __restrict__ h,
                                                  const int* __restrict__ row_ptr,
                                                  const int* __restrict__ csr_src,
                                                  const float* __restrict__ als,
                                                  const float* __restrict__ ald,
                                                  const float* __restrict__ bias,
                                                  float* __restrict__ out,
                                                  int do_elu) {
    int lane = threadIdx.x & 63;
    int w = blockIdx.x * 4 + (threadIdx.x >> 6);
    int v = w >> 3, hd = w & 7;
    if (v >= NN) return;
    float adst = ald[v * NHEADS + hd];
    int s0 = row_ptr[v], s1 = row_ptr[v + 1];
    float m = -INFINITY, l = 0.f, acc = 0.f;
    for (int i = s0; i < s1; i++) {
        int u = csr_src[i];
        float e = als[u * NHEADS + hd] + adst;
        e = (e > 0.f) ? e : NEG_SLOPE * e;
        float nm = fmaxf(m, e);
        float sc = __expf(m - nm);    // 0 on first iter (m = -inf)
        float p  = __expf(e - nm);
        float x  = h[(size_t)u * HCV + hd * HID + lane];
        l   = l * sc + p;
        acc = acc * sc + p * x;
        m = nm;
    }
    float o = acc / (l + 1e-16f) + bias[hd * HID + lane];
    if (do_elu) o = (o > 0.f) ? o : (__expf(o) - 1.f);
    out[(size_t)v * HCV + hd * HID + lane] = o;
}

// layer 3: 1 head, 128 channels, no ELU, writes final output
__global__ __launch_bounds__(256) void agg3_kernel(const float* __restrict__ h,
                                                   const int* __restrict__ row_ptr,
                                                   const int* __restrict__ csr_src,
                                                   const float* __restrict__ als,
                                                   const float* __restrict__ ald,
                                                   const float* __restrict__ bias,
                                                   float* __restrict__ out) {
    int lane = threadIdx.x & 63;
    int v = blockIdx.x * 4 + (threadIdx.x >> 6);
    if (v >= NN) return;
    float adst = ald[v];
    int s0 = row_ptr[v], s1 = row_ptr[v + 1];
    float m = -INFINITY, l = 0.f, acc0 = 0.f, acc1 = 0.f;
    for (int i = s0; i < s1; i++) {
        int u = csr_src[i];
        float e = als[u] + adst;
        e = (e > 0.f) ? e : NEG_SLOPE * e;
        float nm = fmaxf(m, e);
        float sc = __expf(m - nm);
        float p  = __expf(e - nm);
        float x0 = h[(size_t)u * OUTD + lane];
        float x1 = h[(size_t)u * OUTD + 64 + lane];
        l    = l * sc + p;
        acc0 = acc0 * sc + p * x0;
        acc1 = acc1 * sc + p * x1;
        m = nm;
    }
    float inv = 1.f / (l + 1e-16f);
    out[(size_t)v * OUTD + lane]      = acc0 * inv + bias[lane];
    out[(size_t)v * OUTD + 64 + lane] = acc1 * inv + bias[64 + lane];
}

// ---------------- launch ----------------

extern "C" void kernel_launch(void* const* d_in, const int* in_sizes, int n_in,
                              void* d_out, int out_size, void* d_ws, size_t ws_size,
                              hipStream_t stream) {
    const float* x     = (const float*)d_in[0];
    const int*   ei    = (const int*)d_in[1];   // [2,E]: first E = src, next E = dst
    const float* W1    = (const float*)d_in[2];
    const float* as1   = (const float*)d_in[3];
    const float* ad1   = (const float*)d_in[4];
    const float* b1    = (const float*)d_in[5];
    const float* W2    = (const float*)d_in[6];
    const float* as2   = (const float*)d_in[7];
    const float* ad2   = (const float*)d_in[8];
    const float* b2    = (const float*)d_in[9];
    const float* W3    = (const float*)d_in[10];
    const float* as3   = (const float*)d_in[11];
    const float* ad3   = (const float*)d_in[12];
    const float* b3    = (const float*)d_in[13];
    float* out = (float*)d_out;

    // workspace carve
    size_t off = 0;
    auto carve = [&](size_t bytes) {
        void* p = (char*)d_ws + off;
        off += (bytes + 255) & ~(size_t)255;
        return p;
    };
    int* row_ptr = (int*)carve((NN + 1) * sizeof(int));
    int* cursor  = (int*)carve(NN * sizeof(int));
    int* csr_src = (int*)carve(ETOT * sizeof(int));
    float* bufA  = (float*)carve((size_t)NN * HCV * sizeof(float));  // pre-agg features h
    float* bufB  = (float*)carve((size_t)NN * HCV * sizeof(float));  // post-agg features g
    float* h3    = (float*)carve((size_t)NN * OUTD * sizeof(float));
    float* als   = (float*)carve((size_t)NN * NHEADS * sizeof(float));
    float* ald   = (float*)carve((size_t)NN * NHEADS * sizeof(float));
    (void)ws_size; (void)n_in; (void)in_sizes; (void)out_size;

    // ---- CSR build (shared by all layers) ----
    zero_i32<<<(NN + 255) / 256, 256, 0, stream>>>(cursor, NN);
    count_kernel<<<(ETOT + 255) / 256, 256, 0, stream>>>(ei, cursor);
    scan_kernel<<<1, 256, 0, stream>>>(cursor, row_ptr);
    init_cursor<<<(NN + 255) / 256, 256, 0, stream>>>(row_ptr, cursor);
    fill_kernel<<<(ETOT + 255) / 256, 256, 0, stream>>>(ei, cursor, csr_src);

    dim3 blk(256);
    int mtiles = (NN + 63) / 64;

    // ---- layer 1 ----
    gemm64<<<dim3(mtiles, HCV / 64), blk, 0, stream>>>(x, W1, bufA, NN, IND, HCV);
    al_kernel<<<(NN * NHEADS) / 4, blk, 0, stream>>>(bufA, as1, ad1, als, ald);
    agg_kernel<<<(NN * NHEADS) / 4, blk, 0, stream>>>(bufA, row_ptr, csr_src, als, ald, b1, bufB, 1);

    // ---- layer 2 ----
    gemm64<<<dim3(mtiles, HCV / 64), blk, 0, stream>>>(bufB, W2, bufA, NN, HCV, HCV);
    al_kernel<<<(NN * NHEADS) / 4, blk, 0, stream>>>(bufA, as2, ad2, als, ald);
    agg_kernel<<<(NN * NHEADS) / 4, blk, 0, stream>>>(bufA, row_ptr, csr_src, als, ald, b2, bufB, 1);

    // ---- layer 3 ----
    gemm64<<<dim3(mtiles, OUTD / 64), blk, 0, stream>>>(bufB, W3, h3, NN, HCV, OUTD);
    al3_kernel<<<(NN + 3) / 4, blk, 0, stream>>>(h3, as3, ad3, als, ald);
    agg3_kernel<<<(NN + 3) / 4, blk, 0, stream>>>(h3, row_ptr, csr_src, als, ald, b3, out);
}

// Round 2
// 904.465 us; speedup vs baseline: 1.1003x; 1.1003x over previous
//
#include <hip/hip_runtime.h>
#include <math.h>

#define NN 20000
#define EE 320000
#define ETOT 340000   // EE + NN self-loops
#define NHEADS 8
#define HID 64
#define HCV 512       // NHEADS*HID
#define IND 128
#define OUTD 128
#define NEG_SLOPE 0.2f

// ---------------- CSR build ----------------

__global__ void zero_i32(int* p, int n) {
    int i = blockIdx.x * blockDim.x + threadIdx.x;
    if (i < n) p[i] = 0;
}

__global__ void count_kernel(const int* __restrict__ ei, int* __restrict__ cnt) {
    int i = blockIdx.x * blockDim.x + threadIdx.x;
    if (i >= ETOT) return;
    int v = (i < EE) ? ei[EE + i] : (i - EE);
    atomicAdd(&cnt[v], 1);
}

// single-block exclusive scan of cnt[NN] -> row_ptr[NN+1]
__global__ void scan_kernel(const int* __restrict__ cnt, int* __restrict__ row_ptr) {
    __shared__ int tot[256];
    __shared__ int pre[256];
    int t = threadIdx.x;
    const int CH = (NN + 255) / 256;
    int base = t * CH;
    int s = 0;
    for (int i = 0; i < CH; i++) {
        int idx = base + i;
        if (idx < NN) s += cnt[idx];
    }
    tot[t] = s;
    __syncthreads();
    if (t == 0) {
        int run = 0;
        for (int j = 0; j < 256; j++) { pre[j] = run; run += tot[j]; }
        row_ptr[NN] = run;
    }
    __syncthreads();
    int run = pre[t];
    for (int i = 0; i < CH; i++) {
        int idx = base + i;
        if (idx < NN) { row_ptr[idx] = run; run += cnt[idx]; }
    }
}

__global__ void init_cursor(const int* __restrict__ row_ptr, int* __restrict__ cursor) {
    int i = blockIdx.x * blockDim.x + threadIdx.x;
    if (i < NN) cursor[i] = row_ptr[i];
}

__global__ void fill_kernel(const int* __restrict__ ei, int* __restrict__ cursor,
                            int* __restrict__ csr_src) {
    int i = blockIdx.x * blockDim.x + threadIdx.x;
    if (i >= ETOT) return;
    int u, v;
    if (i < EE) { u = ei[i]; v = ei[EE + i]; }
    else        { u = i - EE; v = i - EE; }
    int pos = atomicAdd(&cursor[v], 1);
    csr_src[pos] = u;
}

// ---------------- GEMM: C[M,Nc] = A[M,K] @ B[K,Nc], fp32 ----------------
__global__ __launch_bounds__(256) void gemm64(const float* __restrict__ A,
                                              const float* __restrict__ B,
                                              float* __restrict__ C,
                                              int M, int K, int Nc) {
    __shared__ float As[16][68];
    __shared__ float Bs[16][64];
    int tid = threadIdx.x;
    int tx = tid & 15, ty = tid >> 4;
    int m0 = blockIdx.x * 64, n0 = blockIdx.y * 64;
    float acc[4][4] = {};
    for (int k0 = 0; k0 < K; k0 += 16) {
        {
            int j = tid & 15;
            int i0 = tid >> 4;
            #pragma unroll
            for (int r = 0; r < 4; r++) {
                int i = i0 + r * 16;
                int m = m0 + i;
                As[j][i] = (m < M) ? A[(size_t)m * K + k0 + j] : 0.f;
            }
        }
        {
            int n = tid & 63;
            int kk0 = tid >> 6;
            #pragma unroll
            for (int r = 0; r < 4; r++) {
                int kk = kk0 + r * 4;
                Bs[kk][n] = B[(size_t)(k0 + kk) * Nc + n0 + n];
            }
        }
        __syncthreads();
        #pragma unroll
        for (int kk = 0; kk < 16; kk++) {
            float4 a4 = *(const float4*)&As[kk][ty * 4];
            float4 b4 = *(const float4*)&Bs[kk][tx * 4];
            float av[4] = {a4.x, a4.y, a4.z, a4.w};
            float bv[4] = {b4.x, b4.y, b4.z, b4.w};
            #pragma unroll
            for (int i = 0; i < 4; i++)
                #pragma unroll
                for (int j = 0; j < 4; j++)
                    acc[i][j] += av[i] * bv[j];
        }
        __syncthreads();
    }
    #pragma unroll
    for (int r = 0; r < 4; r++) {
        int m = m0 + ty * 4 + r;
        if (m < M) {
            float4 v = make_float4(acc[r][0], acc[r][1], acc[r][2], acc[r][3]);
            *(float4*)&C[(size_t)m * Nc + n0 + tx * 4] = v;
        }
    }
}

// ---------------- attention half-logits ----------------
__global__ __launch_bounds__(256) void al_kernel(const float* __restrict__ h,
                                                 const float* __restrict__ a_src,
                                                 const float* __restrict__ a_dst,
                                                 float* __restrict__ als,
                                                 float* __restrict__ ald) {
    int lane = threadIdx.x & 63;
    int w = blockIdx.x * 4 + (threadIdx.x >> 6);
    int n = w >> 3, hd = w & 7;
    if (n >= NN) return;
    float v = h[(size_t)n * HCV + hd * HID + lane];
    float s = v * a_src[hd * HID + lane];
    float d = v * a_dst[hd * HID + lane];
    for (int off = 32; off > 0; off >>= 1) {
        s += __shfl_down(s, off);
        d += __shfl_down(d, off);
    }
    if (lane == 0) {
        als[n * NHEADS + hd] = s;
        ald[n * NHEADS + hd] = d;
    }
}

__global__ __launch_bounds__(256) void al3_kernel(const float* __restrict__ h,
                                                  const float* __restrict__ a_src,
                                                  const float* __restrict__ a_dst,
                                                  float* __restrict__ als,
                                                  float* __restrict__ ald) {
    int lane = threadIdx.x & 63;
    int n = blockIdx.x * 4 + (threadIdx.x >> 6);
    if (n >= NN) return;
    float v0 = h[(size_t)n * OUTD + lane];
    float v1 = h[(size_t)n * OUTD + 64 + lane];
    float s = v0 * a_src[lane] + v1 * a_src[64 + lane];
    float d = v0 * a_dst[lane] + v1 * a_dst[64 + lane];
    for (int off = 32; off > 0; off >>= 1) {
        s += __shfl_down(s, off);
        d += __shfl_down(d, off);
    }
    if (lane == 0) { als[n] = s; ald[n] = d; }
}

// ---------------- edge softmax: alpha (unnormalized) + 1/den ----------------
// one wave per (dst,head); LANES OVER EDGES. alpha layout: [NHEADS][ETOT].
__global__ __launch_bounds__(256) void alpha_kernel(const int* __restrict__ row_ptr,
                                                    const int* __restrict__ csr_src,
                                                    const float* __restrict__ als,
                                                    const float* __restrict__ ald,
                                                    float* __restrict__ alpha,
                                                    float* __restrict__ invden) {
    int lane = threadIdx.x & 63;
    int w = blockIdx.x * 4 + (threadIdx.x >> 6);
    int v = w >> 3, hd = w & 7;
    if (v >= NN) return;
    float adst = ald[v * NHEADS + hd];
    int s0 = row_ptr[v], s1 = row_ptr[v + 1];
    // pass 1: max
    float m = -INFINITY;
    for (int base = s0; base < s1; base += 64) {
        int i = base + lane;
        float e = -INFINITY;
        if (i < s1) {
            int u = csr_src[i];
            float t = als[u * NHEADS + hd] + adst;
            e = (t > 0.f) ? t : NEG_SLOPE * t;
        }
        m = fmaxf(m, e);
    }
    #pragma unroll
    for (int off = 32; off > 0; off >>= 1) m = fmaxf(m, __shfl_xor(m, off));
    // pass 2: p = exp(e-m), store, sum
    float l = 0.f;
    for (int base = s0; base < s1; base += 64) {
        int i = base + lane;
        if (i < s1) {
            int u = csr_src[i];
            float t = als[u * NHEADS + hd] + adst;
            t = (t > 0.f) ? t : NEG_SLOPE * t;
            float p = __expf(t - m);
            alpha[(size_t)hd * ETOT + i] = p;
            l += p;
        }
    }
    #pragma unroll
    for (int off = 32; off > 0; off >>= 1) l += __shfl_xor(l, off);
    if (lane == 0) invden[v * NHEADS + hd] = 1.f / (l + 1e-16f);
}

// layer 3 variant (1 head)
__global__ __launch_bounds__(256) void alpha3_kernel(const int* __restrict__ row_ptr,
                                                     const int* __restrict__ csr_src,
                                                     const float* __restrict__ als,
                                                     const float* __restrict__ ald,
                                                     float* __restrict__ alpha,
                                                     float* __restrict__ invden) {
    int lane = threadIdx.x & 63;
    int v = blockIdx.x * 4 + (threadIdx.x >> 6);
    if (v >= NN) return;
    float adst = ald[v];
    int s0 = row_ptr[v], s1 = row_ptr[v + 1];
    float m = -INFINITY;
    for (int base = s0; base < s1; base += 64) {
        int i = base + lane;
        float e = -INFINITY;
        if (i < s1) {
            int u = csr_src[i];
            float t = als[u] + adst;
            e = (t > 0.f) ? t : NEG_SLOPE * t;
        }
        m = fmaxf(m, e);
    }
    #pragma unroll
    for (int off = 32; off > 0; off >>= 1) m = fmaxf(m, __shfl_xor(m, off));
    float l = 0.f;
    for (int base = s0; base < s1; base += 64) {
        int i = base + lane;
        if (i < s1) {
            int u = csr_src[i];
            float t = als[u] + adst;
            t = (t > 0.f) ? t : NEG_SLOPE * t;
            float p = __expf(t - m);
            alpha[i] = p;
            l += p;
        }
    }
    #pragma unroll
    for (int off = 32; off > 0; off >>= 1) l += __shfl_xor(l, off);
    if (lane == 0) invden[v] = 1.f / (l + 1e-16f);
}

// ---------------- weighted feature gather ----------------
// one wave per (dst,head); lane = channel; pure FMA gather, unroll 2.
__global__ __launch_bounds__(256) void gather_kernel(const float* __restrict__ h,
                                                     const int* __restrict__ row_ptr,
                                                     const int* __restrict__ csr_src,
                                                     const float* __restrict__ alpha,
                                                     const float* __restrict__ invden,
                                                     const float* __restrict__ bias,
                                                     float* __restrict__ out,
                                                     int do_elu) {
    int lane = threadIdx.x & 63;
    int w = blockIdx.x * 4 + (threadIdx.x >> 6);
    int v = w >> 3, hd = w & 7;
    if (v >= NN) return;
    int s0 = row_ptr[v], s1 = row_ptr[v + 1];
    const float* ap = alpha + (size_t)hd * ETOT;
    float acc = 0.f;
    int i = s0;
    for (; i + 2 <= s1; i += 2) {
        int u0 = csr_src[i], u1 = csr_src[i + 1];
        float p0 = ap[i], p1 = ap[i + 1];
        float x0 = h[(size_t)u0 * HCV + hd * HID + lane];
        float x1 = h[(size_t)u1 * HCV + hd * HID + lane];
        acc = fmaf(p0, x0, acc);
        acc = fmaf(p1, x1, acc);
    }
    if (i < s1) {
        int u = csr_src[i];
        acc = fmaf(ap[i], h[(size_t)u * HCV + hd * HID + lane], acc);
    }
    float o = acc * invden[v * NHEADS + hd] + bias[hd * HID + lane];
    if (do_elu) o = (o > 0.f) ? o : (__expf(o) - 1.f);
    out[(size_t)v * HCV + hd * HID + lane] = o;
}

// layer 3: 1 head, 128 channels, writes final output
__global__ __launch_bounds__(256) void gather3_kernel(const float* __restrict__ h,
                                                      const int* __restrict__ row_ptr,
                                                      const int* __restrict__ csr_src,
                                                      const float* __restrict__ alpha,
                                                      const float* __restrict__ invden,
                                                      const float* __restrict__ bias,
                                                      float* __restrict__ out) {
    int lane = threadIdx.x & 63;
    int v = blockIdx.x * 4 + (threadIdx.x >> 6);
    if (v >= NN) return;
    int s0 = row_ptr[v], s1 = row_ptr[v + 1];
    float acc0 = 0.f, acc1 = 0.f;
    for (int i = s0; i < s1; i++) {
        int u = csr_src[i];
        float p = alpha[i];
        float x0 = h[(size_t)u * OUTD + lane];
        float x1 = h[(size_t)u * OUTD + 64 + lane];
        acc0 = fmaf(p, x0, acc0);
        acc1 = fmaf(p, x1, acc1);
    }
    float inv = invden[v];
    out[(size_t)v * OUTD + lane]      = acc0 * inv + bias[lane];
    out[(size_t)v * OUTD + 64 + lane] = acc1 * inv + bias[64 + lane];
}

// ---------------- launch ----------------

extern "C" void kernel_launch(void* const* d_in, const int* in_sizes, int n_in,
                              void* d_out, int out_size, void* d_ws, size_t ws_size,
                              hipStream_t stream) {
    const float* x     = (const float*)d_in[0];
    const int*   ei    = (const int*)d_in[1];
    const float* W1    = (const float*)d_in[2];
    const float* as1   = (const float*)d_in[3];
    const float* ad1   = (const float*)d_in[4];
    const float* b1    = (const float*)d_in[5];
    const float* W2    = (const float*)d_in[6];
    const float* as2   = (const float*)d_in[7];
    const float* ad2   = (const float*)d_in[8];
    const float* b2    = (const float*)d_in[9];
    const float* W3    = (const float*)d_in[10];
    const float* as3   = (const float*)d_in[11];
    const float* ad3   = (const float*)d_in[12];
    const float* b3    = (const float*)d_in[13];
    float* out = (float*)d_out;

    size_t off = 0;
    auto carve = [&](size_t bytes) {
        void* p = (char*)d_ws + off;
        off += (bytes + 255) & ~(size_t)255;
        return p;
    };
    int* row_ptr  = (int*)carve((NN + 1) * sizeof(int));
    int* cursor   = (int*)carve(NN * sizeof(int));
    int* csr_src  = (int*)carve(ETOT * sizeof(int));
    float* bufA   = (float*)carve((size_t)NN * HCV * sizeof(float));  // pre-agg h (and h3 in L3)
    float* bufB   = (float*)carve((size_t)NN * HCV * sizeof(float));  // post-agg g
    float* als    = (float*)carve((size_t)NN * NHEADS * sizeof(float));
    float* ald    = (float*)carve((size_t)NN * NHEADS * sizeof(float));
    float* alpha  = (float*)carve((size_t)NHEADS * ETOT * sizeof(float));
    float* invden = (float*)carve((size_t)NN * NHEADS * sizeof(float));
    (void)ws_size; (void)n_in; (void)in_sizes; (void)out_size;

    // ---- CSR build ----
    zero_i32<<<(NN + 255) / 256, 256, 0, stream>>>(cursor, NN);
    count_kernel<<<(ETOT + 255) / 256, 256, 0, stream>>>(ei, cursor);
    scan_kernel<<<1, 256, 0, stream>>>(cursor, row_ptr);
    init_cursor<<<(NN + 255) / 256, 256, 0, stream>>>(row_ptr, cursor);
    fill_kernel<<<(ETOT + 255) / 256, 256, 0, stream>>>(ei, cursor, csr_src);

    dim3 blk(256);
    int mtiles = (NN + 63) / 64;
    int nwaves_nh = (NN * NHEADS + 3) / 4;   // blocks for (node,head) wave kernels
    int nwaves_n  = (NN + 3) / 4;

    // ---- layer 1 ----
    gemm64<<<dim3(mtiles, HCV / 64), blk, 0, stream>>>(x, W1, bufA, NN, IND, HCV);
    al_kernel<<<nwaves_nh, blk, 0, stream>>>(bufA, as1, ad1, als, ald);
    alpha_kernel<<<nwaves_nh, blk, 0, stream>>>(row_ptr, csr_src, als, ald, alpha, invden);
    gather_kernel<<<nwaves_nh, blk, 0, stream>>>(bufA, row_ptr, csr_src, alpha, invden, b1, bufB, 1);

    // ---- layer 2 ----
    gemm64<<<dim3(mtiles, HCV / 64), blk, 0, stream>>>(bufB, W2, bufA, NN, HCV, HCV);
    al_kernel<<<nwaves_nh, blk, 0, stream>>>(bufA, as2, ad2, als, ald);
    alpha_kernel<<<nwaves_nh, blk, 0, stream>>>(row_ptr, csr_src, als, ald, alpha, invden);
    gather_kernel<<<nwaves_nh, blk, 0, stream>>>(bufA, row_ptr, csr_src, alpha, invden, b2, bufB, 1);

    // ---- layer 3 (h3 lives in bufA) ----
    gemm64<<<dim3(mtiles, OUTD / 64), blk, 0, stream>>>(bufB, W3, bufA, NN, HCV, OUTD);
    al3_kernel<<<nwaves_n, blk, 0, stream>>>(bufA, as3, ad3, als, ald);
    alpha3_kernel<<<nwaves_n, blk, 0, stream>>>(row_ptr, csr_src, als, ald, alpha, invden);
    gather3_kernel<<<nwaves_n, blk, 0, stream>>>(bufA, row_ptr, csr_src, alpha, invden, b3, out);
}

// Round 3
// 826.345 us; speedup vs baseline: 1.2043x; 1.0945x over previous
//
#include <hip/hip_runtime.h>
#include <math.h>

#define NN 20000
#define EE 320000
#define ETOT 340000   // EE + NN self-loops
#define NHEADS 8
#define HID 64
#define HCV 512       // NHEADS*HID
#define IND 128
#define OUTD 128
#define NEG_SLOPE 0.2f
#define LDA 132       // 128 + 4 pad, keeps float4 alignment

// ---------------- CSR build ----------------

__global__ void zero_i32(int* p, int n) {
    int i = blockIdx.x * blockDim.x + threadIdx.x;
    if (i < n) p[i] = 0;
}

__global__ void count_kernel(const int* __restrict__ ei, int* __restrict__ cnt) {
    int i = blockIdx.x * blockDim.x + threadIdx.x;
    if (i >= ETOT) return;
    int v = (i < EE) ? ei[EE + i] : (i - EE);
    atomicAdd(&cnt[v], 1);
}

__global__ void scan_kernel(const int* __restrict__ cnt, int* __restrict__ row_ptr) {
    __shared__ int tot[256];
    __shared__ int pre[256];
    int t = threadIdx.x;
    const int CH = (NN + 255) / 256;
    int base = t * CH;
    int s = 0;
    for (int i = 0; i < CH; i++) {
        int idx = base + i;
        if (idx < NN) s += cnt[idx];
    }
    tot[t] = s;
    __syncthreads();
    if (t == 0) {
        int run = 0;
        for (int j = 0; j < 256; j++) { pre[j] = run; run += tot[j]; }
        row_ptr[NN] = run;
    }
    __syncthreads();
    int run = pre[t];
    for (int i = 0; i < CH; i++) {
        int idx = base + i;
        if (idx < NN) { row_ptr[idx] = run; run += cnt[idx]; }
    }
}

__global__ void init_cursor(const int* __restrict__ row_ptr, int* __restrict__ cursor) {
    int i = blockIdx.x * blockDim.x + threadIdx.x;
    if (i < NN) cursor[i] = row_ptr[i];
}

__global__ void fill_kernel(const int* __restrict__ ei, int* __restrict__ cursor,
                            int* __restrict__ csr_src) {
    int i = blockIdx.x * blockDim.x + threadIdx.x;
    if (i >= ETOT) return;
    int u, v;
    if (i < EE) { u = ei[i]; v = ei[EE + i]; }
    else        { u = i - EE; v = i - EE; }
    int pos = atomicAdd(&cursor[v], 1);
    csr_src[pos] = u;
}

// ---------------- GEMM 128x128 tile, 8x8 microtile (N multiple of 128) ----------------
__global__ __launch_bounds__(256) void gemm128(const float* __restrict__ A,
                                               const float* __restrict__ B,
                                               float* __restrict__ C,
                                               int M, int K, int Nc) {
    __shared__ __align__(16) float As[16][LDA];   // [k][m] (A transposed in LDS)
    __shared__ __align__(16) float Bs[16][LDA];   // [k][n]
    int tid = threadIdx.x;
    int tx = tid & 15, ty = tid >> 4;
    int m0 = blockIdx.x * 128, n0 = blockIdx.y * 128;
    float acc[8][8] = {};
    for (int k0 = 0; k0 < K; k0 += 16) {
        // A tile: 128 m x 16 k -> As[k][m]; lanes 0-15 read consecutive k (64B seg)
        {
            int k = tid & 15;
            int mb = tid >> 4;
            #pragma unroll
            for (int r = 0; r < 8; r++) {
                int m = mb + r * 16;
                int gm = m0 + m;
                As[k][m] = (gm < M) ? A[(size_t)gm * K + k0 + k] : 0.f;
            }
        }
        // B tile: 16 k x 128 n, float4 coalesced
        {
            int n4 = (tid & 31) * 4;
            int kb = tid >> 5;
            #pragma unroll
            for (int r = 0; r < 2; r++) {
                int kk = kb + r * 8;
                *(float4*)&Bs[kk][n4] = *(const float4*)&B[(size_t)(k0 + kk) * Nc + n0 + n4];
            }
        }
        __syncthreads();
        #pragma unroll
        for (int kk = 0; kk < 16; kk++) {
            float a[8], b[8];
            *(float4*)&a[0] = *(const float4*)&As[kk][ty * 8];
            *(float4*)&a[4] = *(const float4*)&As[kk][ty * 8 + 4];
            *(float4*)&b[0] = *(const float4*)&Bs[kk][tx * 8];
            *(float4*)&b[4] = *(const float4*)&Bs[kk][tx * 8 + 4];
            #pragma unroll
            for (int i = 0; i < 8; i++)
                #pragma unroll
                for (int j = 0; j < 8; j++)
                    acc[i][j] = fmaf(a[i], b[j], acc[i][j]);
        }
        __syncthreads();
    }
    #pragma unroll
    for (int i = 0; i < 8; i++) {
        int gm = m0 + ty * 8 + i;
        if (gm < M) {
            *(float4*)&C[(size_t)gm * Nc + n0 + tx * 8] =
                make_float4(acc[i][0], acc[i][1], acc[i][2], acc[i][3]);
            *(float4*)&C[(size_t)gm * Nc + n0 + tx * 8 + 4] =
                make_float4(acc[i][4], acc[i][5], acc[i][6], acc[i][7]);
        }
    }
}

// ---------------- GEMM 64x64 tile (kept for layer 3, N=128) ----------------
__global__ __launch_bounds__(256) void gemm64(const float* __restrict__ A,
                                              const float* __restrict__ B,
                                              float* __restrict__ C,
                                              int M, int K, int Nc) {
    __shared__ float As[16][68];
    __shared__ float Bs[16][64];
    int tid = threadIdx.x;
    int tx = tid & 15, ty = tid >> 4;
    int m0 = blockIdx.x * 64, n0 = blockIdx.y * 64;
    float acc[4][4] = {};
    for (int k0 = 0; k0 < K; k0 += 16) {
        {
            int j = tid & 15;
            int i0 = tid >> 4;
            #pragma unroll
            for (int r = 0; r < 4; r++) {
                int i = i0 + r * 16;
                int m = m0 + i;
                As[j][i] = (m < M) ? A[(size_t)m * K + k0 + j] : 0.f;
            }
        }
        {
            int n = tid & 63;
            int kk0 = tid >> 6;
            #pragma unroll
            for (int r = 0; r < 4; r++) {
                int kk = kk0 + r * 4;
                Bs[kk][n] = B[(size_t)(k0 + kk) * Nc + n0 + n];
            }
        }
        __syncthreads();
        #pragma unroll
        for (int kk = 0; kk < 16; kk++) {
            float4 a4 = *(const float4*)&As[kk][ty * 4];
            float4 b4 = *(const float4*)&Bs[kk][tx * 4];
            float av[4] = {a4.x, a4.y, a4.z, a4.w};
            float bv[4] = {b4.x, b4.y, b4.z, b4.w};
            #pragma unroll
            for (int i = 0; i < 4; i++)
                #pragma unroll
                for (int j = 0; j < 4; j++)
                    acc[i][j] = fmaf(av[i], bv[j], acc[i][j]);
        }
        __syncthreads();
    }
    #pragma unroll
    for (int r = 0; r < 4; r++) {
        int m = m0 + ty * 4 + r;
        if (m < M) {
            float4 v = make_float4(acc[r][0], acc[r][1], acc[r][2], acc[r][3]);
            *(float4*)&C[(size_t)m * Nc + n0 + tx * 4] = v;
        }
    }
}

// ---------------- attention half-logits ----------------
__global__ __launch_bounds__(256) void al_kernel(const float* __restrict__ h,
                                                 const float* __restrict__ a_src,
                                                 const float* __restrict__ a_dst,
                                                 float* __restrict__ als,
                                                 float* __restrict__ ald) {
    int lane = threadIdx.x & 63;
    int w = blockIdx.x * 4 + (threadIdx.x >> 6);
    int n = w >> 3, hd = w & 7;
    if (n >= NN) return;
    float v = h[(size_t)n * HCV + hd * HID + lane];
    float s = v * a_src[hd * HID + lane];
    float d = v * a_dst[hd * HID + lane];
    for (int off = 32; off > 0; off >>= 1) {
        s += __shfl_down(s, off);
        d += __shfl_down(d, off);
    }
    if (lane == 0) {
        als[n * NHEADS + hd] = s;
        ald[n * NHEADS + hd] = d;
    }
}

__global__ __launch_bounds__(256) void al3_kernel(const float* __restrict__ h,
                                                  const float* __restrict__ a_src,
                                                  const float* __restrict__ a_dst,
                                                  float* __restrict__ als,
                                                  float* __restrict__ ald) {
    int lane = threadIdx.x & 63;
    int n = blockIdx.x * 4 + (threadIdx.x >> 6);
    if (n >= NN) return;
    float v0 = h[(size_t)n * OUTD + lane];
    float v1 = h[(size_t)n * OUTD + 64 + lane];
    float s = v0 * a_src[lane] + v1 * a_src[64 + lane];
    float d = v0 * a_dst[lane] + v1 * a_dst[64 + lane];
    for (int off = 32; off > 0; off >>= 1) {
        s += __shfl_down(s, off);
        d += __shfl_down(d, off);
    }
    if (lane == 0) { als[n] = s; ald[n] = d; }
}

// ---------------- edge softmax: alpha (unnormalized) + 1/den ----------------
__global__ __launch_bounds__(256) void alpha_kernel(const int* __restrict__ row_ptr,
                                                    const int* __restrict__ csr_src,
                                                    const float* __restrict__ als,
                                                    const float* __restrict__ ald,
                                                    float* __restrict__ alpha,
                                                    float* __restrict__ invden) {
    int lane = threadIdx.x & 63;
    int w = blockIdx.x * 4 + (threadIdx.x >> 6);
    int v = w >> 3, hd = w & 7;
    if (v >= NN) return;
    float adst = ald[v * NHEADS + hd];
    int s0 = row_ptr[v], s1 = row_ptr[v + 1];
    float m = -INFINITY;
    for (int base = s0; base < s1; base += 64) {
        int i = base + lane;
        float e = -INFINITY;
        if (i < s1) {
            int u = csr_src[i];
            float t = als[u * NHEADS + hd] + adst;
            e = (t > 0.f) ? t : NEG_SLOPE * t;
        }
        m = fmaxf(m, e);
    }
    #pragma unroll
    for (int off = 32; off > 0; off >>= 1) m = fmaxf(m, __shfl_xor(m, off));
    float l = 0.f;
    for (int base = s0; base < s1; base += 64) {
        int i = base + lane;
        if (i < s1) {
            int u = csr_src[i];
            float t = als[u * NHEADS + hd] + adst;
            t = (t > 0.f) ? t : NEG_SLOPE * t;
            float p = __expf(t - m);
            alpha[(size_t)hd * ETOT + i] = p;
            l += p;
        }
    }
    #pragma unroll
    for (int off = 32; off > 0; off >>= 1) l += __shfl_xor(l, off);
    if (lane == 0) invden[v * NHEADS + hd] = 1.f / (l + 1e-16f);
}

__global__ __launch_bounds__(256) void alpha3_kernel(const int* __restrict__ row_ptr,
                                                     const int* __restrict__ csr_src,
                                                     const float* __restrict__ als,
                                                     const float* __restrict__ ald,
                                                     float* __restrict__ alpha,
                                                     float* __restrict__ invden) {
    int lane = threadIdx.x & 63;
    int v = blockIdx.x * 4 + (threadIdx.x >> 6);
    if (v >= NN) return;
    float adst = ald[v];
    int s0 = row_ptr[v], s1 = row_ptr[v + 1];
    float m = -INFINITY;
    for (int base = s0; base < s1; base += 64) {
        int i = base + lane;
        float e = -INFINITY;
        if (i < s1) {
            int u = csr_src[i];
            float t = als[u] + adst;
            e = (t > 0.f) ? t : NEG_SLOPE * t;
        }
        m = fmaxf(m, e);
    }
    #pragma unroll
    for (int off = 32; off > 0; off >>= 1) m = fmaxf(m, __shfl_xor(m, off));
    float l = 0.f;
    for (int base = s0; base < s1; base += 64) {
        int i = base + lane;
        if (i < s1) {
            int u = csr_src[i];
            float t = als[u] + adst;
            t = (t > 0.f) ? t : NEG_SLOPE * t;
            float p = __expf(t - m);
            alpha[i] = p;
            l += p;
        }
    }
    #pragma unroll
    for (int off = 32; off > 0; off >>= 1) l += __shfl_xor(l, off);
    if (lane == 0) invden[v] = 1.f / (l + 1e-16f);
}

// ---------------- weighted feature gather, float4 lanes ----------------
// wave per (v,hd); lane = (edge-subgroup 0..3, channel-group 0..15); 4 edges/iter.
__global__ __launch_bounds__(256) void gather_kernel(const float* __restrict__ h,
                                                     const int* __restrict__ row_ptr,
                                                     const int* __restrict__ csr_src,
                                                     const float* __restrict__ alpha,
                                                     const float* __restrict__ invden,
                                                     const float* __restrict__ bias,
                                                     float* __restrict__ out,
                                                     int do_elu) {
    int lane = threadIdx.x & 63;
    int w = blockIdx.x * 4 + (threadIdx.x >> 6);
    int v = w >> 3, hd = w & 7;
    if (v >= NN) return;
    int e_sub = lane >> 4;
    int cg = lane & 15;
    int s0 = row_ptr[v], s1 = row_ptr[v + 1];
    const float* ap = alpha + (size_t)hd * ETOT;
    float4 acc = make_float4(0.f, 0.f, 0.f, 0.f);
    for (int base = s0; base < s1; base += 4) {
        int i = base + e_sub;
        if (i < s1) {
            int u = csr_src[i];
            float p = ap[i];
            float4 x = *(const float4*)&h[(size_t)u * HCV + hd * HID + cg * 4];
            acc.x = fmaf(p, x.x, acc.x);
            acc.y = fmaf(p, x.y, acc.y);
            acc.z = fmaf(p, x.z, acc.z);
            acc.w = fmaf(p, x.w, acc.w);
        }
    }
    #pragma unroll
    for (int off = 16; off <= 32; off <<= 1) {
        acc.x += __shfl_xor(acc.x, off);
        acc.y += __shfl_xor(acc.y, off);
        acc.z += __shfl_xor(acc.z, off);
        acc.w += __shfl_xor(acc.w, off);
    }
    if (e_sub == 0) {
        float inv = invden[v * NHEADS + hd];
        float4 b4 = *(const float4*)&bias[hd * HID + cg * 4];
        float o0 = fmaf(acc.x, inv, b4.x);
        float o1 = fmaf(acc.y, inv, b4.y);
        float o2 = fmaf(acc.z, inv, b4.z);
        float o3 = fmaf(acc.w, inv, b4.w);
        if (do_elu) {
            o0 = (o0 > 0.f) ? o0 : (__expf(o0) - 1.f);
            o1 = (o1 > 0.f) ? o1 : (__expf(o1) - 1.f);
            o2 = (o2 > 0.f) ? o2 : (__expf(o2) - 1.f);
            o3 = (o3 > 0.f) ? o3 : (__expf(o3) - 1.f);
        }
        *(float4*)&out[(size_t)v * HCV + hd * HID + cg * 4] = make_float4(o0, o1, o2, o3);
    }
}

// layer 3: 1 head x 128 ch; lane = (edge-subgroup 0..1, channel-group 0..31)
__global__ __launch_bounds__(256) void gather3_kernel(const float* __restrict__ h,
                                                      const int* __restrict__ row_ptr,
                                                      const int* __restrict__ csr_src,
                                                      const float* __restrict__ alpha,
                                                      const float* __restrict__ invden,
                                                      const float* __restrict__ bias,
                                                      float* __restrict__ out) {
    int lane = threadIdx.x & 63;
    int v = blockIdx.x * 4 + (threadIdx.x >> 6);
    if (v >= NN) return;
    int e_sub = lane >> 5;
    int cg = lane & 31;
    int s0 = row_ptr[v], s1 = row_ptr[v + 1];
    float4 acc = make_float4(0.f, 0.f, 0.f, 0.f);
    for (int base = s0; base < s1; base += 2) {
        int i = base + e_sub;
        if (i < s1) {
            int u = csr_src[i];
            float p = alpha[i];
            float4 x = *(const float4*)&h[(size_t)u * OUTD + cg * 4];
            acc.x = fmaf(p, x.x, acc.x);
            acc.y = fmaf(p, x.y, acc.y);
            acc.z = fmaf(p, x.z, acc.z);
            acc.w = fmaf(p, x.w, acc.w);
        }
    }
    acc.x += __shfl_xor(acc.x, 32);
    acc.y += __shfl_xor(acc.y, 32);
    acc.z += __shfl_xor(acc.z, 32);
    acc.w += __shfl_xor(acc.w, 32);
    if (e_sub == 0) {
        float inv = invden[v];
        float4 b4 = *(const float4*)&bias[cg * 4];
        float4 o = make_float4(fmaf(acc.x, inv, b4.x), fmaf(acc.y, inv, b4.y),
                               fmaf(acc.z, inv, b4.z), fmaf(acc.w, inv, b4.w));
        *(float4*)&out[(size_t)v * OUTD + cg * 4] = o;
    }
}

// ---------------- launch ----------------

extern "C" void kernel_launch(void* const* d_in, const int* in_sizes, int n_in,
                              void* d_out, int out_size, void* d_ws, size_t ws_size,
                              hipStream_t stream) {
    const float* x     = (const float*)d_in[0];
    const int*   ei    = (const int*)d_in[1];
    const float* W1    = (const float*)d_in[2];
    const float* as1   = (const float*)d_in[3];
    const float* ad1   = (const float*)d_in[4];
    const float* b1    = (const float*)d_in[5];
    const float* W2    = (const float*)d_in[6];
    const float* as2   = (const float*)d_in[7];
    const float* ad2   = (const float*)d_in[8];
    const float* b2    = (const float*)d_in[9];
    const float* W3    = (const float*)d_in[10];
    const float* as3   = (const float*)d_in[11];
    const float* ad3   = (const float*)d_in[12];
    const float* b3    = (const float*)d_in[13];
    float* out = (float*)d_out;

    size_t off = 0;
    auto carve = [&](size_t bytes) {
        void* p = (char*)d_ws + off;
        off += (bytes + 255) & ~(size_t)255;
        return p;
    };
    int* row_ptr  = (int*)carve((NN + 1) * sizeof(int));
    int* cursor   = (int*)carve(NN * sizeof(int));
    int* csr_src  = (int*)carve(ETOT * sizeof(int));
    float* bufA   = (float*)carve((size_t)NN * HCV * sizeof(float));
    float* bufB   = (float*)carve((size_t)NN * HCV * sizeof(float));
    float* als    = (float*)carve((size_t)NN * NHEADS * sizeof(float));
    float* ald    = (float*)carve((size_t)NN * NHEADS * sizeof(float));
    float* alpha  = (float*)carve((size_t)NHEADS * ETOT * sizeof(float));
    float* invden = (float*)carve((size_t)NN * NHEADS * sizeof(float));
    (void)ws_size; (void)n_in; (void)in_sizes; (void)out_size;

    // ---- CSR build ----
    zero_i32<<<(NN + 255) / 256, 256, 0, stream>>>(cursor, NN);
    count_kernel<<<(ETOT + 255) / 256, 256, 0, stream>>>(ei, cursor);
    scan_kernel<<<1, 256, 0, stream>>>(cursor, row_ptr);
    init_cursor<<<(NN + 255) / 256, 256, 0, stream>>>(row_ptr, cursor);
    fill_kernel<<<(ETOT + 255) / 256, 256, 0, stream>>>(ei, cursor, csr_src);

    dim3 blk(256);
    int mt128 = (NN + 127) / 128;
    int mt64  = (NN + 63) / 64;
    int nwaves_nh = (NN * NHEADS + 3) / 4;
    int nwaves_n  = (NN + 3) / 4;

    // ---- layer 1 ----
    gemm128<<<dim3(mt128, HCV / 128), blk, 0, stream>>>(x, W1, bufA, NN, IND, HCV);
    al_kernel<<<nwaves_nh, blk, 0, stream>>>(bufA, as1, ad1, als, ald);
    alpha_kernel<<<nwaves_nh, blk, 0, stream>>>(row_ptr, csr_src, als, ald, alpha, invden);
    gather_kernel<<<nwaves_nh, blk, 0, stream>>>(bufA, row_ptr, csr_src, alpha, invden, b1, bufB, 1);

    // ---- layer 2 ----
    gemm128<<<dim3(mt128, HCV / 128), blk, 0, stream>>>(bufB, W2, bufA, NN, HCV, HCV);
    al_kernel<<<nwaves_nh, blk, 0, stream>>>(bufA, as2, ad2, als, ald);
    alpha_kernel<<<nwaves_nh, blk, 0, stream>>>(row_ptr, csr_src, als, ald, alpha, invden);
    gather_kernel<<<nwaves_nh, blk, 0, stream>>>(bufA, row_ptr, csr_src, alpha, invden, b2, bufB, 1);

    // ---- layer 3 (h3 in bufA) ----
    gemm64<<<dim3(mt64, OUTD / 64), blk, 0, stream>>>(bufB, W3, bufA, NN, HCV, OUTD);
    al3_kernel<<<nwaves_n, blk, 0, stream>>>(bufA, as3, ad3, als, ald);
    alpha3_kernel<<<nwaves_n, blk, 0, stream>>>(row_ptr, csr_src, als, ald, alpha, invden);
    gather3_kernel<<<nwaves_n, blk, 0, stream>>>(bufA, row_ptr, csr_src, alpha, invden, b3, out);
}

// Round 4
// 652.160 us; speedup vs baseline: 1.5260x; 1.2671x over previous
//
#include <hip/hip_runtime.h>
#include <math.h>

#define NN 20000
#define EE 320000
#define ETOT 340000   // EE + NN self-loops
#define NHEADS 8
#define HID 64
#define HCV 512       // NHEADS*HID
#define IND 128
#define OUTD 128
#define NEG_SLOPE 0.2f

typedef __attribute__((ext_vector_type(8))) short short8;
typedef __attribute__((ext_vector_type(4))) float floatx4;

__device__ __forceinline__ ushort bf16_rne(float f) {
    union { float f; unsigned u; } v; v.f = f;
    unsigned u = v.u;
    unsigned r = (u + 0x7FFFu + ((u >> 16) & 1u)) >> 16;
    return (ushort)r;
}
__device__ __forceinline__ float bf16_to_f(ushort h) {
    union { unsigned u; float f; } v; v.u = ((unsigned)h) << 16;
    return v.f;
}

// ---------------- CSR build ----------------

__global__ void zero_i32(int* p, int n) {
    int i = blockIdx.x * blockDim.x + threadIdx.x;
    if (i < n) p[i] = 0;
}

__global__ void count_kernel(const int* __restrict__ ei, int* __restrict__ cnt) {
    int i = blockIdx.x * blockDim.x + threadIdx.x;
    if (i >= ETOT) return;
    int v = (i < EE) ? ei[EE + i] : (i - EE);
    atomicAdd(&cnt[v], 1);
}

__global__ void scan_kernel(const int* __restrict__ cnt, int* __restrict__ row_ptr) {
    __shared__ int tot[256];
    __shared__ int pre[256];
    int t = threadIdx.x;
    const int CH = (NN + 255) / 256;
    int base = t * CH;
    int s = 0;
    for (int i = 0; i < CH; i++) {
        int idx = base + i;
        if (idx < NN) s += cnt[idx];
    }
    tot[t] = s;
    __syncthreads();
    if (t == 0) {
        int run = 0;
        for (int j = 0; j < 256; j++) { pre[j] = run; run += tot[j]; }
        row_ptr[NN] = run;
    }
    __syncthreads();
    int run = pre[t];
    for (int i = 0; i < CH; i++) {
        int idx = base + i;
        if (idx < NN) { row_ptr[idx] = run; run += cnt[idx]; }
    }
}

__global__ void init_cursor(const int* __restrict__ row_ptr, int* __restrict__ cursor) {
    int i = blockIdx.x * blockDim.x + threadIdx.x;
    if (i < NN) cursor[i] = row_ptr[i];
}

__global__ void fill_kernel(const int* __restrict__ ei, int* __restrict__ cursor,
                            int* __restrict__ csr_src) {
    int i = blockIdx.x * blockDim.x + threadIdx.x;
    if (i >= ETOT) return;
    int u, v;
    if (i < EE) { u = ei[i]; v = ei[EE + i]; }
    else        { u = i - EE; v = i - EE; }
    int pos = atomicAdd(&cursor[v], 1);
    csr_src[pos] = u;
}

// ---------------- weight transpose + bf16 hi/lo split ----------------
// W [K][N] fp32 -> WT hi/lo [N][K] bf16
__global__ void cvt_wT(const float* __restrict__ W, ushort* __restrict__ Thi,
                       ushort* __restrict__ Tlo, int K, int N) {
    int idx = blockIdx.x * blockDim.x + threadIdx.x;
    if (idx >= K * N) return;
    int k = idx / N, n = idx - k * N;
    float f = W[idx];
    ushort hi = bf16_rne(f);
    ushort lo = bf16_rne(f - bf16_to_f(hi));
    Thi[(size_t)n * K + k] = hi;
    Tlo[(size_t)n * K + k] = lo;
}

// ---------------- MFMA GEMM: C[M,Nc] = A[M,K] @ B[K,Nc] ----------------
// A given as bf16 hi/lo [M][K] (or fp32 [M][K] if Alo==nullptr: split in-kernel).
// B given as transposed bf16 hi/lo [Nc][K]. 128x128 tile, 4 waves (2x2), BK=32.
// 3-term split: Ahi*Bhi + Ahi*Blo + Alo*Bhi -> ~fp32 accuracy.
#define LDK 40   // ushorts per LDS row: 32 data + 8 pad (2-way bank alias, 16B aligned)
__global__ __launch_bounds__(256) void gemm_mfma(const void* __restrict__ Ahi_,
                                                 const ushort* __restrict__ Alo,
                                                 const ushort* __restrict__ Bhi,
                                                 const ushort* __restrict__ Blo,
                                                 float* __restrict__ C,
                                                 int M, int K, int Nc) {
    __shared__ ushort sA[2][128 * LDK];
    __shared__ ushort sB[2][128 * LDK];
    int tid = threadIdx.x;
    int lane = tid & 63;
    int wv = tid >> 6;
    int wr = wv >> 1, wc = wv & 1;
    int m0 = blockIdx.x * 128, n0 = blockIdx.y * 128;
    int quad = lane >> 4;
    int l15 = lane & 15;
    int arow = tid >> 2;   // 0..63
    int ac4 = tid & 3;     // 16B chunk within 64B row-slice

    floatx4 acc[4][4] = {};
    const bool split_a = (Alo == nullptr);
    const ushort* Ahi = (const ushort*)Ahi_;
    const float* Af = (const float*)Ahi_;

    for (int k0 = 0; k0 < K; k0 += 32) {
        #pragma unroll
        for (int r = 0; r < 2; r++) {
            int row = arow + r * 64;
            int gm = m0 + row;
            if (split_a) {
                ushort h[8], l[8];
                if (gm < M) {
                    const float* src = &Af[(size_t)gm * K + k0 + ac4 * 8];
                    #pragma unroll
                    for (int j = 0; j < 8; j++) {
                        float f = src[j];
                        h[j] = bf16_rne(f);
                        l[j] = bf16_rne(f - bf16_to_f(h[j]));
                    }
                } else {
                    #pragma unroll
                    for (int j = 0; j < 8; j++) { h[j] = 0; l[j] = 0; }
                }
                #pragma unroll
                for (int j = 0; j < 8; j++) {
                    sA[0][row * LDK + ac4 * 8 + j] = h[j];
                    sA[1][row * LDK + ac4 * 8 + j] = l[j];
                }
            } else {
                int4 vh, vl;
                if (gm < M) {
                    vh = *(const int4*)&Ahi[(size_t)gm * K + k0 + ac4 * 8];
                    vl = *(const int4*)&Alo[(size_t)gm * K + k0 + ac4 * 8];
                } else {
                    vh = make_int4(0, 0, 0, 0); vl = vh;
                }
                *(int4*)&sA[0][row * LDK + ac4 * 8] = vh;
                *(int4*)&sA[1][row * LDK + ac4 * 8] = vl;
            }
            int gn = n0 + row;   // Nc is a multiple of 128
            int4 bh = *(const int4*)&Bhi[(size_t)gn * K + k0 + ac4 * 8];
            int4 bl = *(const int4*)&Blo[(size_t)gn * K + k0 + ac4 * 8];
            *(int4*)&sB[0][row * LDK + ac4 * 8] = bh;
            *(int4*)&sB[1][row * LDK + ac4 * 8] = bl;
        }
        __syncthreads();
        short8 a_hi[4], a_lo[4], b_hi[4], b_lo[4];
        #pragma unroll
        for (int i = 0; i < 4; i++) {
            int am = wr * 64 + i * 16 + l15;
            a_hi[i] = *(const short8*)&sA[0][am * LDK + quad * 8];
            a_lo[i] = *(const short8*)&sA[1][am * LDK + quad * 8];
            int bn = wc * 64 + i * 16 + l15;
            b_hi[i] = *(const short8*)&sB[0][bn * LDK + quad * 8];
            b_lo[i] = *(const short8*)&sB[1][bn * LDK + quad * 8];
        }
        #pragma unroll
        for (int i = 0; i < 4; i++)
            #pragma unroll
            for (int j = 0; j < 4; j++) {
                acc[i][j] = __builtin_amdgcn_mfma_f32_16x16x32_bf16(a_hi[i], b_hi[j], acc[i][j], 0, 0, 0);
                acc[i][j] = __builtin_amdgcn_mfma_f32_16x16x32_bf16(a_hi[i], b_lo[j], acc[i][j], 0, 0, 0);
                acc[i][j] = __builtin_amdgcn_mfma_f32_16x16x32_bf16(a_lo[i], b_hi[j], acc[i][j], 0, 0, 0);
            }
        __syncthreads();
    }
    // C/D layout: col = lane&15, row = quad*4 + reg  [verified m89/m91]
    #pragma unroll
    for (int i = 0; i < 4; i++) {
        #pragma unroll
        for (int r = 0; r < 4; r++) {
            int gm = m0 + wr * 64 + i * 16 + quad * 4 + r;
            if (gm < M) {
                #pragma unroll
                for (int j = 0; j < 4; j++)
                    C[(size_t)gm * Nc + n0 + wc * 64 + j * 16 + l15] = acc[i][j][r];
            }
        }
    }
}

// ---------------- attention half-logits ----------------
__global__ __launch_bounds__(256) void al_kernel(const float* __restrict__ h,
                                                 const float* __restrict__ a_src,
                                                 const float* __restrict__ a_dst,
                                                 float* __restrict__ als,
                                                 float* __restrict__ ald) {
    int lane = threadIdx.x & 63;
    int w = blockIdx.x * 4 + (threadIdx.x >> 6);
    int n = w >> 3, hd = w & 7;
    if (n >= NN) return;
    float v = h[(size_t)n * HCV + hd * HID + lane];
    float s = v * a_src[hd * HID + lane];
    float d = v * a_dst[hd * HID + lane];
    for (int off = 32; off > 0; off >>= 1) {
        s += __shfl_down(s, off);
        d += __shfl_down(d, off);
    }
    if (lane == 0) {
        als[n * NHEADS + hd] = s;
        ald[n * NHEADS + hd] = d;
    }
}

__global__ __launch_bounds__(256) void al3_kernel(const float* __restrict__ h,
                                                  const float* __restrict__ a_src,
                                                  const float* __restrict__ a_dst,
                                                  float* __restrict__ als,
                                                  float* __restrict__ ald) {
    int lane = threadIdx.x & 63;
    int n = blockIdx.x * 4 + (threadIdx.x >> 6);
    if (n >= NN) return;
    float v0 = h[(size_t)n * OUTD + lane];
    float v1 = h[(size_t)n * OUTD + 64 + lane];
    float s = v0 * a_src[lane] + v1 * a_src[64 + lane];
    float d = v0 * a_dst[lane] + v1 * a_dst[64 + lane];
    for (int off = 32; off > 0; off >>= 1) {
        s += __shfl_down(s, off);
        d += __shfl_down(d, off);
    }
    if (lane == 0) { als[n] = s; ald[n] = d; }
}

// ---------------- edge softmax: alpha (unnormalized, bf16) + 1/den ----------------
__global__ __launch_bounds__(256) void alpha_kernel(const int* __restrict__ row_ptr,
                                                    const int* __restrict__ csr_src,
                                                    const float* __restrict__ als,
                                                    const float* __restrict__ ald,
                                                    ushort* __restrict__ alpha,
                                                    float* __restrict__ invden) {
    int lane = threadIdx.x & 63;
    int w = blockIdx.x * 4 + (threadIdx.x >> 6);
    int v = w >> 3, hd = w & 7;
    if (v >= NN) return;
    float adst = ald[v * NHEADS + hd];
    int s0 = row_ptr[v], s1 = row_ptr[v + 1];
    float m = -INFINITY;
    for (int base = s0; base < s1; base += 64) {
        int i = base + lane;
        float e = -INFINITY;
        if (i < s1) {
            int u = csr_src[i];
            float t = als[u * NHEADS + hd] + adst;
            e = (t > 0.f) ? t : NEG_SLOPE * t;
        }
        m = fmaxf(m, e);
    }
    #pragma unroll
    for (int off = 32; off > 0; off >>= 1) m = fmaxf(m, __shfl_xor(m, off));
    float l = 0.f;
    for (int base = s0; base < s1; base += 64) {
        int i = base + lane;
        if (i < s1) {
            int u = csr_src[i];
            float t = als[u * NHEADS + hd] + adst;
            t = (t > 0.f) ? t : NEG_SLOPE * t;
            ushort pa = bf16_rne(__expf(t - m));
            alpha[(size_t)hd * ETOT + i] = pa;
            l += bf16_to_f(pa);
        }
    }
    #pragma unroll
    for (int off = 32; off > 0; off >>= 1) l += __shfl_xor(l, off);
    if (lane == 0) invden[v * NHEADS + hd] = 1.f / (l + 1e-16f);
}

__global__ __launch_bounds__(256) void alpha3_kernel(const int* __restrict__ row_ptr,
                                                     const int* __restrict__ csr_src,
                                                     const float* __restrict__ als,
                                                     const float* __restrict__ ald,
                                                     ushort* __restrict__ alpha,
                                                     float* __restrict__ invden) {
    int lane = threadIdx.x & 63;
    int v = blockIdx.x * 4 + (threadIdx.x >> 6);
    if (v >= NN) return;
    float adst = ald[v];
    int s0 = row_ptr[v], s1 = row_ptr[v + 1];
    float m = -INFINITY;
    for (int base = s0; base < s1; base += 64) {
        int i = base + lane;
        float e = -INFINITY;
        if (i < s1) {
            int u = csr_src[i];
            float t = als[u] + adst;
            e = (t > 0.f) ? t : NEG_SLOPE * t;
        }
        m = fmaxf(m, e);
    }
    #pragma unroll
    for (int off = 32; off > 0; off >>= 1) m = fmaxf(m, __shfl_xor(m, off));
    float l = 0.f;
    for (int base = s0; base < s1; base += 64) {
        int i = base + lane;
        if (i < s1) {
            int u = csr_src[i];
            float t = als[u] + adst;
            t = (t > 0.f) ? t : NEG_SLOPE * t;
            ushort pa = bf16_rne(__expf(t - m));
            alpha[i] = pa;
            l += bf16_to_f(pa);
        }
    }
    #pragma unroll
    for (int off = 32; off > 0; off >>= 1) l += __shfl_xor(l, off);
    if (lane == 0) invden[v] = 1.f / (l + 1e-16f);
}

// ---------------- weighted feature gather (layers 1/2) ----------------
// wave per (v,hd); lane = (edge-subgroup 0..3, channel-group 0..15); 4 edges/iter.
// Output: bf16 hi/lo (feeds next MFMA GEMM).
__global__ __launch_bounds__(256) void gather_kernel(const float* __restrict__ h,
                                                     const int* __restrict__ row_ptr,
                                                     const int* __restrict__ csr_src,
                                                     const ushort* __restrict__ alpha,
                                                     const float* __restrict__ invden,
                                                     const float* __restrict__ bias,
                                                     ushort* __restrict__ ghi,
                                                     ushort* __restrict__ glo) {
    int lane = threadIdx.x & 63;
    int w = blockIdx.x * 4 + (threadIdx.x >> 6);
    int v = w >> 3, hd = w & 7;
    if (v >= NN) return;
    int e_sub = lane >> 4;
    int cg = lane & 15;
    int s0 = row_ptr[v], s1 = row_ptr[v + 1];
    const ushort* ap = alpha + (size_t)hd * ETOT;
    float4 acc = make_float4(0.f, 0.f, 0.f, 0.f);
    for (int base = s0; base < s1; base += 4) {
        int i = base + e_sub;
        if (i < s1) {
            int u = csr_src[i];
            float p = bf16_to_f(ap[i]);
            float4 x = *(const float4*)&h[(size_t)u * HCV + hd * HID + cg * 4];
            acc.x = fmaf(p, x.x, acc.x);
            acc.y = fmaf(p, x.y, acc.y);
            acc.z = fmaf(p, x.z, acc.z);
            acc.w = fmaf(p, x.w, acc.w);
        }
    }
    #pragma unroll
    for (int off = 16; off <= 32; off <<= 1) {
        acc.x += __shfl_xor(acc.x, off);
        acc.y += __shfl_xor(acc.y, off);
        acc.z += __shfl_xor(acc.z, off);
        acc.w += __shfl_xor(acc.w, off);
    }
    if (e_sub == 0) {
        float inv = invden[v * NHEADS + hd];
        float4 b4 = *(const float4*)&bias[hd * HID + cg * 4];
        float o[4];
        o[0] = fmaf(acc.x, inv, b4.x);
        o[1] = fmaf(acc.y, inv, b4.y);
        o[2] = fmaf(acc.z, inv, b4.z);
        o[3] = fmaf(acc.w, inv, b4.w);
        ushort4 h4, l4;
        ushort* hp = (ushort*)&h4;
        ushort* lp = (ushort*)&l4;
        #pragma unroll
        for (int j = 0; j < 4; j++) {
            float e = o[j];
            e = (e > 0.f) ? e : (__expf(e) - 1.f);   // ELU
            ushort hb = bf16_rne(e);
            hp[j] = hb;
            lp[j] = bf16_rne(e - bf16_to_f(hb));
        }
        size_t idx = (size_t)v * HCV + hd * HID + cg * 4;
        *(ushort4*)&ghi[idx] = h4;
        *(ushort4*)&glo[idx] = l4;
    }
}

// layer 3: fp32 output to d_out
__global__ __launch_bounds__(256) void gather3_kernel(const float* __restrict__ h,
                                                      const int* __restrict__ row_ptr,
                                                      const int* __restrict__ csr_src,
                                                      const ushort* __restrict__ alpha,
                                                      const float* __restrict__ invden,
                                                      const float* __restrict__ bias,
                                                      float* __restrict__ out) {
    int lane = threadIdx.x & 63;
    int v = blockIdx.x * 4 + (threadIdx.x >> 6);
    if (v >= NN) return;
    int e_sub = lane >> 5;
    int cg = lane & 31;
    int s0 = row_ptr[v], s1 = row_ptr[v + 1];
    float4 acc = make_float4(0.f, 0.f, 0.f, 0.f);
    for (int base = s0; base < s1; base += 2) {
        int i = base + e_sub;
        if (i < s1) {
            int u = csr_src[i];
            float p = bf16_to_f(alpha[i]);
            float4 x = *(const float4*)&h[(size_t)u * OUTD + cg * 4];
            acc.x = fmaf(p, x.x, acc.x);
            acc.y = fmaf(p, x.y, acc.y);
            acc.z = fmaf(p, x.z, acc.z);
            acc.w = fmaf(p, x.w, acc.w);
        }
    }
    acc.x += __shfl_xor(acc.x, 32);
    acc.y += __shfl_xor(acc.y, 32);
    acc.z += __shfl_xor(acc.z, 32);
    acc.w += __shfl_xor(acc.w, 32);
    if (e_sub == 0) {
        float inv = invden[v];
        float4 b4 = *(const float4*)&bias[cg * 4];
        float4 o = make_float4(fmaf(acc.x, inv, b4.x), fmaf(acc.y, inv, b4.y),
                               fmaf(acc.z, inv, b4.z), fmaf(acc.w, inv, b4.w));
        *(float4*)&out[(size_t)v * OUTD + cg * 4] = o;
    }
}

// ---------------- launch ----------------

extern "C" void kernel_launch(void* const* d_in, const int* in_sizes, int n_in,
                              void* d_out, int out_size, void* d_ws, size_t ws_size,
                              hipStream_t stream) {
    const float* x     = (const float*)d_in[0];
    const int*   ei    = (const int*)d_in[1];
    const float* W1    = (const float*)d_in[2];
    const float* as1   = (const float*)d_in[3];
    const float* ad1   = (const float*)d_in[4];
    const float* b1    = (const float*)d_in[5];
    const float* W2    = (const float*)d_in[6];
    const float* as2   = (const float*)d_in[7];
    const float* ad2   = (const float*)d_in[8];
    const float* b2    = (const float*)d_in[9];
    const float* W3    = (const float*)d_in[10];
    const float* as3   = (const float*)d_in[11];
    const float* ad3   = (const float*)d_in[12];
    const float* b3    = (const float*)d_in[13];
    float* out = (float*)d_out;

    size_t off = 0;
    auto carve = [&](size_t bytes) {
        void* p = (char*)d_ws + off;
        off += (bytes + 255) & ~(size_t)255;
        return p;
    };
    int* row_ptr  = (int*)carve((NN + 1) * sizeof(int));
    int* cursor   = (int*)carve(NN * sizeof(int));
    int* csr_src  = (int*)carve(ETOT * sizeof(int));
    float* bufA   = (float*)carve((size_t)NN * HCV * sizeof(float));   // h (fp32 GEMM out)
    ushort* ghi   = (ushort*)carve((size_t)NN * HCV * sizeof(ushort)); // activations hi
    ushort* glo   = (ushort*)carve((size_t)NN * HCV * sizeof(ushort)); // activations lo
    float* als    = (float*)carve((size_t)NN * NHEADS * sizeof(float));
    float* ald    = (float*)carve((size_t)NN * NHEADS * sizeof(float));
    ushort* alpha = (ushort*)carve((size_t)NHEADS * ETOT * sizeof(ushort));
    float* invden = (float*)carve((size_t)NN * NHEADS * sizeof(float));
    ushort* W1Th  = (ushort*)carve((size_t)HCV * IND * sizeof(ushort));
    ushort* W1Tl  = (ushort*)carve((size_t)HCV * IND * sizeof(ushort));
    ushort* W2Th  = (ushort*)carve((size_t)HCV * HCV * sizeof(ushort));
    ushort* W2Tl  = (ushort*)carve((size_t)HCV * HCV * sizeof(ushort));
    ushort* W3Th  = (ushort*)carve((size_t)OUTD * HCV * sizeof(ushort));
    ushort* W3Tl  = (ushort*)carve((size_t)OUTD * HCV * sizeof(ushort));
    (void)ws_size; (void)n_in; (void)in_sizes; (void)out_size;

    dim3 blk(256);

    // ---- weight prep ----
    cvt_wT<<<(IND * HCV + 255) / 256, blk, 0, stream>>>(W1, W1Th, W1Tl, IND, HCV);
    cvt_wT<<<(HCV * HCV + 255) / 256, blk, 0, stream>>>(W2, W2Th, W2Tl, HCV, HCV);
    cvt_wT<<<(HCV * OUTD + 255) / 256, blk, 0, stream>>>(W3, W3Th, W3Tl, HCV, OUTD);

    // ---- CSR build ----
    zero_i32<<<(NN + 255) / 256, blk, 0, stream>>>(cursor, NN);
    count_kernel<<<(ETOT + 255) / 256, blk, 0, stream>>>(ei, cursor);
    scan_kernel<<<1, blk, 0, stream>>>(cursor, row_ptr);
    init_cursor<<<(NN + 255) / 256, blk, 0, stream>>>(row_ptr, cursor);
    fill_kernel<<<(ETOT + 255) / 256, blk, 0, stream>>>(ei, cursor, csr_src);

    int mt = (NN + 127) / 128;
    int nwaves_nh = (NN * NHEADS + 3) / 4;
    int nwaves_n  = (NN + 3) / 4;

    // ---- layer 1 (A = fp32 x, split in-kernel) ----
    gemm_mfma<<<dim3(mt, HCV / 128), blk, 0, stream>>>(x, nullptr, W1Th, W1Tl, bufA, NN, IND, HCV);
    al_kernel<<<nwaves_nh, blk, 0, stream>>>(bufA, as1, ad1, als, ald);
    alpha_kernel<<<nwaves_nh, blk, 0, stream>>>(row_ptr, csr_src, als, ald, alpha, invden);
    gather_kernel<<<nwaves_nh, blk, 0, stream>>>(bufA, row_ptr, csr_src, alpha, invden, b1, ghi, glo);

    // ---- layer 2 ----
    gemm_mfma<<<dim3(mt, HCV / 128), blk, 0, stream>>>(ghi, glo, W2Th, W2Tl, bufA, NN, HCV, HCV);
    al_kernel<<<nwaves_nh, blk, 0, stream>>>(bufA, as2, ad2, als, ald);
    alpha_kernel<<<nwaves_nh, blk, 0, stream>>>(row_ptr, csr_src, als, ald, alpha, invden);
    gather_kernel<<<nwaves_nh, blk, 0, stream>>>(bufA, row_ptr, csr_src, alpha, invden, b2, ghi, glo);

    // ---- layer 3 (h3 in bufA[0 .. NN*OUTD)) ----
    gemm_mfma<<<dim3(mt, OUTD / 128), blk, 0, stream>>>(ghi, glo, W3Th, W3Tl, bufA, NN, HCV, OUTD);
    al3_kernel<<<nwaves_n, blk, 0, stream>>>(bufA, as3, ad3, als, ald);
    alpha3_kernel<<<nwaves_n, blk, 0, stream>>>(row_ptr, csr_src, als, ald, alpha, invden);
    gather3_kernel<<<nwaves_n, blk, 0, stream>>>(bufA, row_ptr, csr_src, alpha, invden, b3, out);
}

// Round 5
// 611.768 us; speedup vs baseline: 1.6268x; 1.0660x over previous
//
#include <hip/hip_runtime.h>
#include <math.h>

#define NN 20000
#define EE 320000
#define ETOT 340000   // EE + NN self-loops
#define NHEADS 8
#define HID 64
#define HCV 512       // NHEADS*HID
#define IND 128
#define OUTD 128
#define NEG_SLOPE 0.2f

typedef __attribute__((ext_vector_type(8))) short short8;
typedef __attribute__((ext_vector_type(8))) unsigned short ushort8;
typedef __attribute__((ext_vector_type(4))) float floatx4;

__device__ __forceinline__ ushort bf16_rne(float f) {
    union { float f; unsigned u; } v; v.f = f;
    unsigned u = v.u;
    unsigned r = (u + 0x7FFFu + ((u >> 16) & 1u)) >> 16;
    return (ushort)r;
}
__device__ __forceinline__ float bf16_to_f(ushort h) {
    union { unsigned u; float f; } v; v.u = ((unsigned)h) << 16;
    return v.f;
}

// ---------------- CSR build ----------------

__global__ void zero_i32(int* p, int n) {
    int i = blockIdx.x * blockDim.x + threadIdx.x;
    if (i < n) p[i] = 0;
}

__global__ void count_kernel(const int* __restrict__ ei, int* __restrict__ cnt) {
    int i = blockIdx.x * blockDim.x + threadIdx.x;
    if (i >= ETOT) return;
    int v = (i < EE) ? ei[EE + i] : (i - EE);
    atomicAdd(&cnt[v], 1);
}

__global__ void scan_kernel(const int* __restrict__ cnt, int* __restrict__ row_ptr) {
    __shared__ int tot[256];
    __shared__ int pre[256];
    int t = threadIdx.x;
    const int CH = (NN + 255) / 256;
    int base = t * CH;
    int s = 0;
    for (int i = 0; i < CH; i++) {
        int idx = base + i;
        if (idx < NN) s += cnt[idx];
    }
    tot[t] = s;
    __syncthreads();
    if (t == 0) {
        int run = 0;
        for (int j = 0; j < 256; j++) { pre[j] = run; run += tot[j]; }
        row_ptr[NN] = run;
    }
    __syncthreads();
    int run = pre[t];
    for (int i = 0; i < CH; i++) {
        int idx = base + i;
        if (idx < NN) { row_ptr[idx] = run; run += cnt[idx]; }
    }
}

__global__ void init_cursor(const int* __restrict__ row_ptr, int* __restrict__ cursor) {
    int i = blockIdx.x * blockDim.x + threadIdx.x;
    if (i < NN) cursor[i] = row_ptr[i];
}

__global__ void fill_kernel(const int* __restrict__ ei, int* __restrict__ cursor,
                            int* __restrict__ csr_src) {
    int i = blockIdx.x * blockDim.x + threadIdx.x;
    if (i >= ETOT) return;
    int u, v;
    if (i < EE) { u = ei[i]; v = ei[EE + i]; }
    else        { u = i - EE; v = i - EE; }
    int pos = atomicAdd(&cursor[v], 1);
    csr_src[pos] = u;
}

// ---------------- weight transpose + bf16 hi/lo split ----------------
__global__ void cvt_wT(const float* __restrict__ W, ushort* __restrict__ Thi,
                       ushort* __restrict__ Tlo, int K, int N) {
    int idx = blockIdx.x * blockDim.x + threadIdx.x;
    if (idx >= K * N) return;
    int k = idx / N, n = idx - k * N;
    float f = W[idx];
    ushort hi = bf16_rne(f);
    ushort lo = bf16_rne(f - bf16_to_f(hi));
    Thi[(size_t)n * K + k] = hi;
    Tlo[(size_t)n * K + k] = lo;
}

// ---------------- MFMA GEMM: C[M,Nc] = A[M,K] @ B[K,Nc] ----------------
// A: bf16 hi/lo [M][K] (or fp32 if Alo==nullptr: split in-kernel).
// B: transposed bf16 hi/lo [Nc][K]. 128x128 tile, 4 waves, BK=32, 3-term split.
// Output: fp32 to C if C16==nullptr, else bf16 to C16.
#define LDK 40
__global__ __launch_bounds__(256) void gemm_mfma(const void* __restrict__ Ahi_,
                                                 const ushort* __restrict__ Alo,
                                                 const ushort* __restrict__ Bhi,
                                                 const ushort* __restrict__ Blo,
                                                 float* __restrict__ C,
                                                 ushort* __restrict__ C16,
                                                 int M, int K, int Nc) {
    __shared__ ushort sA[2][128 * LDK];
    __shared__ ushort sB[2][128 * LDK];
    int tid = threadIdx.x;
    int lane = tid & 63;
    int wv = tid >> 6;
    int wr = wv >> 1, wc = wv & 1;
    int m0 = blockIdx.x * 128, n0 = blockIdx.y * 128;
    int quad = lane >> 4;
    int l15 = lane & 15;
    int arow = tid >> 2;
    int ac4 = tid & 3;

    floatx4 acc[4][4] = {};
    const bool split_a = (Alo == nullptr);
    const ushort* Ahi = (const ushort*)Ahi_;
    const float* Af = (const float*)Ahi_;

    for (int k0 = 0; k0 < K; k0 += 32) {
        #pragma unroll
        for (int r = 0; r < 2; r++) {
            int row = arow + r * 64;
            int gm = m0 + row;
            if (split_a) {
                ushort h[8], l[8];
                if (gm < M) {
                    const float* src = &Af[(size_t)gm * K + k0 + ac4 * 8];
                    #pragma unroll
                    for (int j = 0; j < 8; j++) {
                        float f = src[j];
                        h[j] = bf16_rne(f);
                        l[j] = bf16_rne(f - bf16_to_f(h[j]));
                    }
                } else {
                    #pragma unroll
                    for (int j = 0; j < 8; j++) { h[j] = 0; l[j] = 0; }
                }
                #pragma unroll
                for (int j = 0; j < 8; j++) {
                    sA[0][row * LDK + ac4 * 8 + j] = h[j];
                    sA[1][row * LDK + ac4 * 8 + j] = l[j];
                }
            } else {
                int4 vh, vl;
                if (gm < M) {
                    vh = *(const int4*)&Ahi[(size_t)gm * K + k0 + ac4 * 8];
                    vl = *(const int4*)&Alo[(size_t)gm * K + k0 + ac4 * 8];
                } else {
                    vh = make_int4(0, 0, 0, 0); vl = vh;
                }
                *(int4*)&sA[0][row * LDK + ac4 * 8] = vh;
                *(int4*)&sA[1][row * LDK + ac4 * 8] = vl;
            }
            int gn = n0 + row;
            int4 bh = *(const int4*)&Bhi[(size_t)gn * K + k0 + ac4 * 8];
            int4 bl = *(const int4*)&Blo[(size_t)gn * K + k0 + ac4 * 8];
            *(int4*)&sB[0][row * LDK + ac4 * 8] = bh;
            *(int4*)&sB[1][row * LDK + ac4 * 8] = bl;
        }
        __syncthreads();
        short8 a_hi[4], a_lo[4], b_hi[4], b_lo[4];
        #pragma unroll
        for (int i = 0; i < 4; i++) {
            int am = wr * 64 + i * 16 + l15;
            a_hi[i] = *(const short8*)&sA[0][am * LDK + quad * 8];
            a_lo[i] = *(const short8*)&sA[1][am * LDK + quad * 8];
            int bn = wc * 64 + i * 16 + l15;
            b_hi[i] = *(const short8*)&sB[0][bn * LDK + quad * 8];
            b_lo[i] = *(const short8*)&sB[1][bn * LDK + quad * 8];
        }
        #pragma unroll
        for (int i = 0; i < 4; i++)
            #pragma unroll
            for (int j = 0; j < 4; j++) {
                acc[i][j] = __builtin_amdgcn_mfma_f32_16x16x32_bf16(a_hi[i], b_hi[j], acc[i][j], 0, 0, 0);
                acc[i][j] = __builtin_amdgcn_mfma_f32_16x16x32_bf16(a_hi[i], b_lo[j], acc[i][j], 0, 0, 0);
                acc[i][j] = __builtin_amdgcn_mfma_f32_16x16x32_bf16(a_lo[i], b_hi[j], acc[i][j], 0, 0, 0);
            }
        __syncthreads();
    }
    // C/D layout: col = lane&15, row = quad*4 + reg
    #pragma unroll
    for (int i = 0; i < 4; i++) {
        #pragma unroll
        for (int r = 0; r < 4; r++) {
            int gm = m0 + wr * 64 + i * 16 + quad * 4 + r;
            if (gm < M) {
                if (C16) {
                    #pragma unroll
                    for (int j = 0; j < 4; j++)
                        C16[(size_t)gm * Nc + n0 + wc * 64 + j * 16 + l15] = bf16_rne(acc[i][j][r]);
                } else {
                    #pragma unroll
                    for (int j = 0; j < 4; j++)
                        C[(size_t)gm * Nc + n0 + wc * 64 + j * 16 + l15] = acc[i][j][r];
                }
            }
        }
    }
}

// ---------------- attention half-logits (layers 1/2: bf16 h) ----------------
__global__ __launch_bounds__(256) void al_kernel(const ushort* __restrict__ h,
                                                 const float* __restrict__ a_src,
                                                 const float* __restrict__ a_dst,
                                                 float* __restrict__ als,
                                                 float* __restrict__ ald) {
    int lane = threadIdx.x & 63;
    int w = blockIdx.x * 4 + (threadIdx.x >> 6);
    int n = w >> 3, hd = w & 7;
    if (n >= NN) return;
    float v = bf16_to_f(h[(size_t)n * HCV + hd * HID + lane]);
    float s = v * a_src[hd * HID + lane];
    float d = v * a_dst[hd * HID + lane];
    for (int off = 32; off > 0; off >>= 1) {
        s += __shfl_down(s, off);
        d += __shfl_down(d, off);
    }
    if (lane == 0) {
        als[n * NHEADS + hd] = s;
        ald[n * NHEADS + hd] = d;
    }
}

__global__ __launch_bounds__(256) void al3_kernel(const float* __restrict__ h,
                                                  const float* __restrict__ a_src,
                                                  const float* __restrict__ a_dst,
                                                  float* __restrict__ als,
                                                  float* __restrict__ ald) {
    int lane = threadIdx.x & 63;
    int n = blockIdx.x * 4 + (threadIdx.x >> 6);
    if (n >= NN) return;
    float v0 = h[(size_t)n * OUTD + lane];
    float v1 = h[(size_t)n * OUTD + 64 + lane];
    float s = v0 * a_src[lane] + v1 * a_src[64 + lane];
    float d = v0 * a_dst[lane] + v1 * a_dst[64 + lane];
    for (int off = 32; off > 0; off >>= 1) {
        s += __shfl_down(s, off);
        d += __shfl_down(d, off);
    }
    if (lane == 0) { als[n] = s; ald[n] = d; }
}

// ---------------- edge softmax: alpha (unnormalized, bf16) + 1/den ----------------
__global__ __launch_bounds__(256) void alpha_kernel(const int* __restrict__ row_ptr,
                                                    const int* __restrict__ csr_src,
                                                    const float* __restrict__ als,
                                                    const float* __restrict__ ald,
                                                    ushort* __restrict__ alpha,
                                                    float* __restrict__ invden) {
    int lane = threadIdx.x & 63;
    int w = blockIdx.x * 4 + (threadIdx.x >> 6);
    int v = w >> 3, hd = w & 7;
    if (v >= NN) return;
    float adst = ald[v * NHEADS + hd];
    int s0 = row_ptr[v], s1 = row_ptr[v + 1];
    float m = -INFINITY;
    for (int base = s0; base < s1; base += 64) {
        int i = base + lane;
        float e = -INFINITY;
        if (i < s1) {
            int u = csr_src[i];
            float t = als[u * NHEADS + hd] + adst;
            e = (t > 0.f) ? t : NEG_SLOPE * t;
        }
        m = fmaxf(m, e);
    }
    #pragma unroll
    for (int off = 32; off > 0; off >>= 1) m = fmaxf(m, __shfl_xor(m, off));
    float l = 0.f;
    for (int base = s0; base < s1; base += 64) {
        int i = base + lane;
        if (i < s1) {
            int u = csr_src[i];
            float t = als[u * NHEADS + hd] + adst;
            t = (t > 0.f) ? t : NEG_SLOPE * t;
            ushort pa = bf16_rne(__expf(t - m));
            alpha[(size_t)hd * ETOT + i] = pa;
            l += bf16_to_f(pa);
        }
    }
    #pragma unroll
    for (int off = 32; off > 0; off >>= 1) l += __shfl_xor(l, off);
    if (lane == 0) invden[v * NHEADS + hd] = 1.f / (l + 1e-16f);
}

__global__ __launch_bounds__(256) void alpha3_kernel(const int* __restrict__ row_ptr,
                                                     const int* __restrict__ csr_src,
                                                     const float* __restrict__ als,
                                                     const float* __restrict__ ald,
                                                     ushort* __restrict__ alpha,
                                                     float* __restrict__ invden) {
    int lane = threadIdx.x & 63;
    int v = blockIdx.x * 4 + (threadIdx.x >> 6);
    if (v >= NN) return;
    float adst = ald[v];
    int s0 = row_ptr[v], s1 = row_ptr[v + 1];
    float m = -INFINITY;
    for (int base = s0; base < s1; base += 64) {
        int i = base + lane;
        float e = -INFINITY;
        if (i < s1) {
            int u = csr_src[i];
            float t = als[u] + adst;
            e = (t > 0.f) ? t : NEG_SLOPE * t;
        }
        m = fmaxf(m, e);
    }
    #pragma unroll
    for (int off = 32; off > 0; off >>= 1) m = fmaxf(m, __shfl_xor(m, off));
    float l = 0.f;
    for (int base = s0; base < s1; base += 64) {
        int i = base + lane;
        if (i < s1) {
            int u = csr_src[i];
            float t = als[u] + adst;
            t = (t > 0.f) ? t : NEG_SLOPE * t;
            ushort pa = bf16_rne(__expf(t - m));
            alpha[i] = pa;
            l += bf16_to_f(pa);
        }
    }
    #pragma unroll
    for (int off = 32; off > 0; off >>= 1) l += __shfl_xor(l, off);
    if (lane == 0) invden[v] = 1.f / (l + 1e-16f);
}

// ---------------- weighted feature gather (layers 1/2, bf16 h) ----------------
// wave per (v,hd); lane = (edge-subgroup 0..7, channel-group 0..7); 8 edges/iter,
// each lane loads ushort8 (16B = 8 channels). Reduce over e_sub via shfl_xor.
__global__ __launch_bounds__(256) void gather_kernel(const ushort* __restrict__ h,
                                                     const int* __restrict__ row_ptr,
                                                     const int* __restrict__ csr_src,
                                                     const ushort* __restrict__ alpha,
                                                     const float* __restrict__ invden,
                                                     const float* __restrict__ bias,
                                                     ushort* __restrict__ ghi,
                                                     ushort* __restrict__ glo) {
    int lane = threadIdx.x & 63;
    int w = blockIdx.x * 4 + (threadIdx.x >> 6);
    int v = w >> 3, hd = w & 7;
    if (v >= NN) return;
    int e_sub = lane >> 3;   // 0..7
    int cg = lane & 7;       // 0..7 (8 channels each)
    int s0 = row_ptr[v], s1 = row_ptr[v + 1];
    const ushort* ap = alpha + (size_t)hd * ETOT;
    float acc[8] = {};
    for (int base = s0; base < s1; base += 8) {
        int i = base + e_sub;
        if (i < s1) {
            int u = csr_src[i];
            float p = bf16_to_f(ap[i]);
            ushort8 xv = *(const ushort8*)&h[(size_t)u * HCV + hd * HID + cg * 8];
            #pragma unroll
            for (int j = 0; j < 8; j++)
                acc[j] = fmaf(p, bf16_to_f(xv[j]), acc[j]);
        }
    }
    #pragma unroll
    for (int off = 8; off <= 32; off <<= 1)
        #pragma unroll
        for (int j = 0; j < 8; j++)
            acc[j] += __shfl_xor(acc[j], off);
    if (e_sub == 0) {
        float inv = invden[v * NHEADS + hd];
        ushort8 hv, lv;
        #pragma unroll
        for (int j = 0; j < 8; j++) {
            float o = fmaf(acc[j], inv, bias[hd * HID + cg * 8 + j]);
            o = (o > 0.f) ? o : (__expf(o) - 1.f);   // ELU
            ushort hb = bf16_rne(o);
            hv[j] = hb;
            lv[j] = bf16_rne(o - bf16_to_f(hb));
        }
        size_t idx = (size_t)v * HCV + hd * HID + cg * 8;
        *(ushort8*)&ghi[idx] = hv;
        *(ushort8*)&glo[idx] = lv;
    }
}

// layer 3: fp32 h3, fp32 output to d_out
__global__ __launch_bounds__(256) void gather3_kernel(const float* __restrict__ h,
                                                      const int* __restrict__ row_ptr,
                                                      const int* __restrict__ csr_src,
                                                      const ushort* __restrict__ alpha,
                                                      const float* __restrict__ invden,
                                                      const float* __restrict__ bias,
                                                      float* __restrict__ out) {
    int lane = threadIdx.x & 63;
    int v = blockIdx.x * 4 + (threadIdx.x >> 6);
    if (v >= NN) return;
    int e_sub = lane >> 5;
    int cg = lane & 31;
    int s0 = row_ptr[v], s1 = row_ptr[v + 1];
    float4 acc = make_float4(0.f, 0.f, 0.f, 0.f);
    for (int base = s0; base < s1; base += 2) {
        int i = base + e_sub;
        if (i < s1) {
            int u = csr_src[i];
            float p = bf16_to_f(alpha[i]);
            float4 x = *(const float4*)&h[(size_t)u * OUTD + cg * 4];
            acc.x = fmaf(p, x.x, acc.x);
            acc.y = fmaf(p, x.y, acc.y);
            acc.z = fmaf(p, x.z, acc.z);
            acc.w = fmaf(p, x.w, acc.w);
        }
    }
    acc.x += __shfl_xor(acc.x, 32);
    acc.y += __shfl_xor(acc.y, 32);
    acc.z += __shfl_xor(acc.z, 32);
    acc.w += __shfl_xor(acc.w, 32);
    if (e_sub == 0) {
        float inv = invden[v];
        float4 b4 = *(const float4*)&bias[cg * 4];
        float4 o = make_float4(fmaf(acc.x, inv, b4.x), fmaf(acc.y, inv, b4.y),
                               fmaf(acc.z, inv, b4.z), fmaf(acc.w, inv, b4.w));
        *(float4*)&out[(size_t)v * OUTD + cg * 4] = o;
    }
}

// ---------------- launch ----------------

extern "C" void kernel_launch(void* const* d_in, const int* in_sizes, int n_in,
                              void* d_out, int out_size, void* d_ws, size_t ws_size,
                              hipStream_t stream) {
    const float* x     = (const float*)d_in[0];
    const int*   ei    = (const int*)d_in[1];
    const float* W1    = (const float*)d_in[2];
    const float* as1   = (const float*)d_in[3];
    const float* ad1   = (const float*)d_in[4];
    const float* b1    = (const float*)d_in[5];
    const float* W2    = (const float*)d_in[6];
    const float* as2   = (const float*)d_in[7];
    const float* ad2   = (const float*)d_in[8];
    const float* b2    = (const float*)d_in[9];
    const float* W3    = (const float*)d_in[10];
    const float* as3   = (const float*)d_in[11];
    const float* ad3   = (const float*)d_in[12];
    const float* b3    = (const float*)d_in[13];
    float* out = (float*)d_out;

    size_t off = 0;
    auto carve = [&](size_t bytes) {
        void* p = (char*)d_ws + off;
        off += (bytes + 255) & ~(size_t)255;
        return p;
    };
    int* row_ptr  = (int*)carve((NN + 1) * sizeof(int));
    int* cursor   = (int*)carve(NN * sizeof(int));
    int* csr_src  = (int*)carve(ETOT * sizeof(int));
    ushort* hb16  = (ushort*)carve((size_t)NN * HCV * sizeof(ushort)); // pre-agg h, bf16 (L1/L2)
    float* bufA   = (float*)carve((size_t)NN * OUTD * sizeof(float));  // h3 fp32 (L3)
    ushort* ghi   = (ushort*)carve((size_t)NN * HCV * sizeof(ushort)); // activations hi
    ushort* glo   = (ushort*)carve((size_t)NN * HCV * sizeof(ushort)); // activations lo
    float* als    = (float*)carve((size_t)NN * NHEADS * sizeof(float));
    float* ald    = (float*)carve((size_t)NN * NHEADS * sizeof(float));
    ushort* alpha = (ushort*)carve((size_t)NHEADS * ETOT * sizeof(ushort));
    float* invden = (float*)carve((size_t)NN * NHEADS * sizeof(float));
    ushort* W1Th  = (ushort*)carve((size_t)HCV * IND * sizeof(ushort));
    ushort* W1Tl  = (ushort*)carve((size_t)HCV * IND * sizeof(ushort));
    ushort* W2Th  = (ushort*)carve((size_t)HCV * HCV * sizeof(ushort));
    ushort* W2Tl  = (ushort*)carve((size_t)HCV * HCV * sizeof(ushort));
    ushort* W3Th  = (ushort*)carve((size_t)OUTD * HCV * sizeof(ushort));
    ushort* W3Tl  = (ushort*)carve((size_t)OUTD * HCV * sizeof(ushort));
    (void)ws_size; (void)n_in; (void)in_sizes; (void)out_size;

    dim3 blk(256);

    // ---- weight prep ----
    cvt_wT<<<(IND * HCV + 255) / 256, blk, 0, stream>>>(W1, W1Th, W1Tl, IND, HCV);
    cvt_wT<<<(HCV * HCV + 255) / 256, blk, 0, stream>>>(W2, W2Th, W2Tl, HCV, HCV);
    cvt_wT<<<(HCV * OUTD + 255) / 256, blk, 0, stream>>>(W3, W3Th, W3Tl, HCV, OUTD);

    // ---- CSR build ----
    zero_i32<<<(NN + 255) / 256, blk, 0, stream>>>(cursor, NN);
    count_kernel<<<(ETOT + 255) / 256, blk, 0, stream>>>(ei, cursor);
    scan_kernel<<<1, blk, 0, stream>>>(cursor, row_ptr);
    init_cursor<<<(NN + 255) / 256, blk, 0, stream>>>(row_ptr, cursor);
    fill_kernel<<<(ETOT + 255) / 256, blk, 0, stream>>>(ei, cursor, csr_src);

    int mt = (NN + 127) / 128;
    int nwaves_nh = (NN * NHEADS + 3) / 4;
    int nwaves_n  = (NN + 3) / 4;

    // ---- layer 1 (A = fp32 x, split in-kernel; C -> bf16 hb16) ----
    gemm_mfma<<<dim3(mt, HCV / 128), blk, 0, stream>>>(x, nullptr, W1Th, W1Tl, nullptr, hb16, NN, IND, HCV);
    al_kernel<<<nwaves_nh, blk, 0, stream>>>(hb16, as1, ad1, als, ald);
    alpha_kernel<<<nwaves_nh, blk, 0, stream>>>(row_ptr, csr_src, als, ald, alpha, invden);
    gather_kernel<<<nwaves_nh, blk, 0, stream>>>(hb16, row_ptr, csr_src, alpha, invden, b1, ghi, glo);

    // ---- layer 2 ----
    gemm_mfma<<<dim3(mt, HCV / 128), blk, 0, stream>>>(ghi, glo, W2Th, W2Tl, nullptr, hb16, NN, HCV, HCV);
    al_kernel<<<nwaves_nh, blk, 0, stream>>>(hb16, as2, ad2, als, ald);
    alpha_kernel<<<nwaves_nh, blk, 0, stream>>>(row_ptr, csr_src, als, ald, alpha, invden);
    gather_kernel<<<nwaves_nh, blk, 0, stream>>>(hb16, row_ptr, csr_src, alpha, invden, b2, ghi, glo);

    // ---- layer 3 (fp32 h3 in bufA) ----
    gemm_mfma<<<dim3(mt, OUTD / 128), blk, 0, stream>>>(ghi, glo, W3Th, W3Tl, bufA, nullptr, NN, HCV, OUTD);
    al3_kernel<<<nwaves_n, blk, 0, stream>>>(bufA, as3, ad3, als, ald);
    alpha3_kernel<<<nwaves_n, blk, 0, stream>>>(row_ptr, csr_src, als, ald, alpha, invden);
    gather3_kernel<<<nwaves_n, blk, 0, stream>>>(bufA, row_ptr, csr_src, alpha, invden, b3, out);
}

// Round 6
// 476.408 us; speedup vs baseline: 2.0890x; 1.2841x over previous
//
#include <hip/hip_runtime.h>
#include <math.h>

#define NN 20000
#define EE 320000
#define ETOT 340000   // EE + NN self-loops
#define NHEADS 8
#define HID 64
#define HCV 512       // NHEADS*HID
#define IND 128
#define OUTD 128
#define NEG_SLOPE 0.2f

typedef __attribute__((ext_vector_type(8))) short short8;
typedef __attribute__((ext_vector_type(8))) unsigned short ushort8;
typedef __attribute__((ext_vector_type(4))) float floatx4;

__device__ __forceinline__ ushort bf16_rne(float f) {
    union { float f; unsigned u; } v; v.f = f;
    unsigned u = v.u;
    unsigned r = (u + 0x7FFFu + ((u >> 16) & 1u)) >> 16;
    return (ushort)r;
}
__device__ __forceinline__ float bf16_to_f(ushort h) {
    union { unsigned u; float f; } v; v.u = ((unsigned)h) << 16;
    return v.f;
}

// ---------------- CSR build ----------------

__global__ void zero_i32(int* p, int n) {
    int i = blockIdx.x * blockDim.x + threadIdx.x;
    if (i < n) p[i] = 0;
}

__global__ void count_kernel(const int* __restrict__ ei, int* __restrict__ cnt) {
    int i = blockIdx.x * blockDim.x + threadIdx.x;
    if (i >= ETOT) return;
    int v = (i < EE) ? ei[EE + i] : (i - EE);
    atomicAdd(&cnt[v], 1);
}

__global__ void scan_kernel(const int* __restrict__ cnt, int* __restrict__ row_ptr) {
    __shared__ int tot[256];
    __shared__ int pre[256];
    int t = threadIdx.x;
    const int CH = (NN + 255) / 256;
    int base = t * CH;
    int s = 0;
    for (int i = 0; i < CH; i++) {
        int idx = base + i;
        if (idx < NN) s += cnt[idx];
    }
    tot[t] = s;
    __syncthreads();
    if (t == 0) {
        int run = 0;
        for (int j = 0; j < 256; j++) { pre[j] = run; run += tot[j]; }
        row_ptr[NN] = run;
    }
    __syncthreads();
    int run = pre[t];
    for (int i = 0; i < CH; i++) {
        int idx = base + i;
        if (idx < NN) { row_ptr[idx] = run; run += cnt[idx]; }
    }
}

__global__ void init_cursor(const int* __restrict__ row_ptr, int* __restrict__ cursor) {
    int i = blockIdx.x * blockDim.x + threadIdx.x;
    if (i < NN) cursor[i] = row_ptr[i];
}

__global__ void fill_kernel(const int* __restrict__ ei, int* __restrict__ cursor,
                            int* __restrict__ csr_src) {
    int i = blockIdx.x * blockDim.x + threadIdx.x;
    if (i >= ETOT) return;
    int u, v;
    if (i < EE) { u = ei[i]; v = ei[EE + i]; }
    else        { u = i - EE; v = i - EE; }
    int pos = atomicAdd(&cursor[v], 1);
    csr_src[pos] = u;
}

// ---------------- weight transpose + bf16 hi/lo split ----------------
__global__ void cvt_wT(const float* __restrict__ W, ushort* __restrict__ Thi,
                       ushort* __restrict__ Tlo, int K, int N) {
    int idx = blockIdx.x * blockDim.x + threadIdx.x;
    if (idx >= K * N) return;
    int k = idx / N, n = idx - k * N;
    float f = W[idx];
    ushort hi = bf16_rne(f);
    ushort lo = bf16_rne(f - bf16_to_f(hi));
    Thi[(size_t)n * K + k] = hi;
    Tlo[(size_t)n * K + k] = lo;
}

// ---------------- MFMA GEMM: C[M,Nc] = A[M,K] @ B[K,Nc] ----------------
#define LDK 40
__global__ __launch_bounds__(256) void gemm_mfma(const void* __restrict__ Ahi_,
                                                 const ushort* __restrict__ Alo,
                                                 const ushort* __restrict__ Bhi,
                                                 const ushort* __restrict__ Blo,
                                                 float* __restrict__ C,
                                                 ushort* __restrict__ C16,
                                                 int M, int K, int Nc) {
    __shared__ ushort sA[2][128 * LDK];
    __shared__ ushort sB[2][128 * LDK];
    int tid = threadIdx.x;
    int lane = tid & 63;
    int wv = tid >> 6;
    int wr = wv >> 1, wc = wv & 1;
    int m0 = blockIdx.x * 128, n0 = blockIdx.y * 128;
    int quad = lane >> 4;
    int l15 = lane & 15;
    int arow = tid >> 2;
    int ac4 = tid & 3;

    floatx4 acc[4][4] = {};
    const bool split_a = (Alo == nullptr);
    const ushort* Ahi = (const ushort*)Ahi_;
    const float* Af = (const float*)Ahi_;

    for (int k0 = 0; k0 < K; k0 += 32) {
        #pragma unroll
        for (int r = 0; r < 2; r++) {
            int row = arow + r * 64;
            int gm = m0 + row;
            if (split_a) {
                ushort h[8], l[8];
                if (gm < M) {
                    const float* src = &Af[(size_t)gm * K + k0 + ac4 * 8];
                    #pragma unroll
                    for (int j = 0; j < 8; j++) {
                        float f = src[j];
                        h[j] = bf16_rne(f);
                        l[j] = bf16_rne(f - bf16_to_f(h[j]));
                    }
                } else {
                    #pragma unroll
                    for (int j = 0; j < 8; j++) { h[j] = 0; l[j] = 0; }
                }
                #pragma unroll
                for (int j = 0; j < 8; j++) {
                    sA[0][row * LDK + ac4 * 8 + j] = h[j];
                    sA[1][row * LDK + ac4 * 8 + j] = l[j];
                }
            } else {
                int4 vh, vl;
                if (gm < M) {
                    vh = *(const int4*)&Ahi[(size_t)gm * K + k0 + ac4 * 8];
                    vl = *(const int4*)&Alo[(size_t)gm * K + k0 + ac4 * 8];
                } else {
                    vh = make_int4(0, 0, 0, 0); vl = vh;
                }
                *(int4*)&sA[0][row * LDK + ac4 * 8] = vh;
                *(int4*)&sA[1][row * LDK + ac4 * 8] = vl;
            }
            int gn = n0 + row;
            int4 bh = *(const int4*)&Bhi[(size_t)gn * K + k0 + ac4 * 8];
            int4 bl = *(const int4*)&Blo[(size_t)gn * K + k0 + ac4 * 8];
            *(int4*)&sB[0][row * LDK + ac4 * 8] = bh;
            *(int4*)&sB[1][row * LDK + ac4 * 8] = bl;
        }
        __syncthreads();
        short8 a_hi[4], a_lo[4], b_hi[4], b_lo[4];
        #pragma unroll
        for (int i = 0; i < 4; i++) {
            int am = wr * 64 + i * 16 + l15;
            a_hi[i] = *(const short8*)&sA[0][am * LDK + quad * 8];
            a_lo[i] = *(const short8*)&sA[1][am * LDK + quad * 8];
            int bn = wc * 64 + i * 16 + l15;
            b_hi[i] = *(const short8*)&sB[0][bn * LDK + quad * 8];
            b_lo[i] = *(const short8*)&sB[1][bn * LDK + quad * 8];
        }
        #pragma unroll
        for (int i = 0; i < 4; i++)
            #pragma unroll
            for (int j = 0; j < 4; j++) {
                acc[i][j] = __builtin_amdgcn_mfma_f32_16x16x32_bf16(a_hi[i], b_hi[j], acc[i][j], 0, 0, 0);
                acc[i][j] = __builtin_amdgcn_mfma_f32_16x16x32_bf16(a_hi[i], b_lo[j], acc[i][j], 0, 0, 0);
                acc[i][j] = __builtin_amdgcn_mfma_f32_16x16x32_bf16(a_lo[i], b_hi[j], acc[i][j], 0, 0, 0);
            }
        __syncthreads();
    }
    // C/D layout: col = lane&15, row = quad*4 + reg
    #pragma unroll
    for (int i = 0; i < 4; i++) {
        #pragma unroll
        for (int r = 0; r < 4; r++) {
            int gm = m0 + wr * 64 + i * 16 + quad * 4 + r;
            if (gm < M) {
                if (C16) {
                    #pragma unroll
                    for (int j = 0; j < 4; j++)
                        C16[(size_t)gm * Nc + n0 + wc * 64 + j * 16 + l15] = bf16_rne(acc[i][j][r]);
                } else {
                    #pragma unroll
                    for (int j = 0; j < 4; j++)
                        C[(size_t)gm * Nc + n0 + wc * 64 + j * 16 + l15] = acc[i][j][r];
                }
            }
        }
    }
}

// ---------------- attention half-logits (layers 1/2: bf16 h) ----------------
__global__ __launch_bounds__(256) void al_kernel(const ushort* __restrict__ h,
                                                 const float* __restrict__ a_src,
                                                 const float* __restrict__ a_dst,
                                                 float* __restrict__ als,
                                                 float* __restrict__ ald) {
    int lane = threadIdx.x & 63;
    int w = blockIdx.x * 4 + (threadIdx.x >> 6);
    int n = w >> 3, hd = w & 7;
    if (n >= NN) return;
    float v = bf16_to_f(h[(size_t)n * HCV + hd * HID + lane]);
    float s = v * a_src[hd * HID + lane];
    float d = v * a_dst[hd * HID + lane];
    for (int off = 32; off > 0; off >>= 1) {
        s += __shfl_down(s, off);
        d += __shfl_down(d, off);
    }
    if (lane == 0) {
        als[n * NHEADS + hd] = s;
        ald[n * NHEADS + hd] = d;
    }
}

__global__ __launch_bounds__(256) void al3_kernel(const float* __restrict__ h,
                                                  const float* __restrict__ a_src,
                                                  const float* __restrict__ a_dst,
                                                  float* __restrict__ als,
                                                  float* __restrict__ ald) {
    int lane = threadIdx.x & 63;
    int n = blockIdx.x * 4 + (threadIdx.x >> 6);
    if (n >= NN) return;
    float v0 = h[(size_t)n * OUTD + lane];
    float v1 = h[(size_t)n * OUTD + 64 + lane];
    float s = v0 * a_src[lane] + v1 * a_src[64 + lane];
    float d = v0 * a_dst[lane] + v1 * a_dst[64 + lane];
    for (int off = 32; off > 0; off >>= 1) {
        s += __shfl_down(s, off);
        d += __shfl_down(d, off);
    }
    if (lane == 0) { als[n] = s; ald[n] = d; }
}

// ---------------- edge softmax (layers 1/2): wave per v, all 8 heads ----------------
// lane = (e_sub 0..7)<<3 | (hd 0..7). alphaT layout: [ETOT][8] bf16.
__global__ __launch_bounds__(256) void alpha_kernel(const int* __restrict__ row_ptr,
                                                    const int* __restrict__ csr_src,
                                                    const float* __restrict__ als,
                                                    const float* __restrict__ ald,
                                                    ushort* __restrict__ alphaT,
                                                    float* __restrict__ invden) {
    int lane = threadIdx.x & 63;
    int v = blockIdx.x * 4 + (threadIdx.x >> 6);
    if (v >= NN) return;
    int e_sub = lane >> 3;
    int hd = lane & 7;
    float adst = ald[v * NHEADS + hd];
    int s0 = row_ptr[v], s1 = row_ptr[v + 1];
    // pass 1: per-head max (reduce across e_sub = lane bits 3..5)
    float m = -INFINITY;
    for (int base = s0; base < s1; base += 8) {
        int i = base + e_sub;
        if (i < s1) {
            int u = csr_src[i];
            float t = als[u * NHEADS + hd] + adst;
            t = (t > 0.f) ? t : NEG_SLOPE * t;
            m = fmaxf(m, t);
        }
    }
    #pragma unroll
    for (int off = 8; off <= 32; off <<= 1) m = fmaxf(m, __shfl_xor(m, off));
    // pass 2: exp, store bf16, per-head sum
    float l = 0.f;
    for (int base = s0; base < s1; base += 8) {
        int i = base + e_sub;
        if (i < s1) {
            int u = csr_src[i];
            float t = als[u * NHEADS + hd] + adst;
            t = (t > 0.f) ? t : NEG_SLOPE * t;
            ushort pa = bf16_rne(__expf(t - m));
            alphaT[(size_t)i * 8 + hd] = pa;
            l += bf16_to_f(pa);
        }
    }
    #pragma unroll
    for (int off = 8; off <= 32; off <<= 1) l += __shfl_xor(l, off);
    if (e_sub == 0) invden[v * NHEADS + hd] = 1.f / (l + 1e-16f);
}

// layer 3 variant (1 head), flat alpha[i]
__global__ __launch_bounds__(256) void alpha3_kernel(const int* __restrict__ row_ptr,
                                                     const int* __restrict__ csr_src,
                                                     const float* __restrict__ als,
                                                     const float* __restrict__ ald,
                                                     ushort* __restrict__ alpha,
                                                     float* __restrict__ invden) {
    int lane = threadIdx.x & 63;
    int v = blockIdx.x * 4 + (threadIdx.x >> 6);
    if (v >= NN) return;
    float adst = ald[v];
    int s0 = row_ptr[v], s1 = row_ptr[v + 1];
    float m = -INFINITY;
    for (int base = s0; base < s1; base += 64) {
        int i = base + lane;
        float e = -INFINITY;
        if (i < s1) {
            int u = csr_src[i];
            float t = als[u] + adst;
            e = (t > 0.f) ? t : NEG_SLOPE * t;
        }
        m = fmaxf(m, e);
    }
    #pragma unroll
    for (int off = 32; off > 0; off >>= 1) m = fmaxf(m, __shfl_xor(m, off));
    float l = 0.f;
    for (int base = s0; base < s1; base += 64) {
        int i = base + lane;
        if (i < s1) {
            int u = csr_src[i];
            float t = als[u] + adst;
            t = (t > 0.f) ? t : NEG_SLOPE * t;
            ushort pa = bf16_rne(__expf(t - m));
            alpha[i] = pa;
            l += bf16_to_f(pa);
        }
    }
    #pragma unroll
    for (int off = 32; off > 0; off >>= 1) l += __shfl_xor(l, off);
    if (lane == 0) invden[v] = 1.f / (l + 1e-16f);
}

// ---------------- weighted feature gather (layers 1/2): wave per v ----------------
// lane owns channels [lane*8, lane*8+8) of 512; head = lane>>3.
// Per edge: 1KB fully-coalesced h row + 16B broadcast alpha row. No reduction.
__global__ __launch_bounds__(256) void gather_kernel(const ushort* __restrict__ h,
                                                     const int* __restrict__ row_ptr,
                                                     const int* __restrict__ csr_src,
                                                     const ushort* __restrict__ alphaT,
                                                     const float* __restrict__ invden,
                                                     const float* __restrict__ bias,
                                                     ushort* __restrict__ ghi,
                                                     ushort* __restrict__ glo) {
    int lane = threadIdx.x & 63;
    int v = blockIdx.x * 4 + (threadIdx.x >> 6);
    if (v >= NN) return;
    int hd = lane >> 3;
    int s0 = row_ptr[v], s1 = row_ptr[v + 1];
    float acc[8] = {};
    int i = s0;
    for (; i + 2 <= s1; i += 2) {
        int u0 = csr_src[i];
        int u1 = csr_src[i + 1];
        float p0 = bf16_to_f(alphaT[(size_t)i * 8 + hd]);
        float p1 = bf16_to_f(alphaT[(size_t)(i + 1) * 8 + hd]);
        ushort8 x0 = *(const ushort8*)&h[(size_t)u0 * HCV + lane * 8];
        ushort8 x1 = *(const ushort8*)&h[(size_t)u1 * HCV + lane * 8];
        #pragma unroll
        for (int j = 0; j < 8; j++) {
            acc[j] = fmaf(p0, bf16_to_f(x0[j]), acc[j]);
            acc[j] = fmaf(p1, bf16_to_f(x1[j]), acc[j]);
        }
    }
    if (i < s1) {
        int u0 = csr_src[i];
        float p0 = bf16_to_f(alphaT[(size_t)i * 8 + hd]);
        ushort8 x0 = *(const ushort8*)&h[(size_t)u0 * HCV + lane * 8];
        #pragma unroll
        for (int j = 0; j < 8; j++)
            acc[j] = fmaf(p0, bf16_to_f(x0[j]), acc[j]);
    }
    float inv = invden[v * NHEADS + hd];
    ushort8 hv, lv;
    #pragma unroll
    for (int j = 0; j < 8; j++) {
        float o = fmaf(acc[j], inv, bias[lane * 8 + j]);
        o = (o > 0.f) ? o : (__expf(o) - 1.f);   // ELU
        ushort hb = bf16_rne(o);
        hv[j] = hb;
        lv[j] = bf16_rne(o - bf16_to_f(hb));
    }
    size_t idx = (size_t)v * HCV + lane * 8;
    *(ushort8*)&ghi[idx] = hv;
    *(ushort8*)&glo[idx] = lv;
}

// layer 3: fp32 h3, fp32 output to d_out
__global__ __launch_bounds__(256) void gather3_kernel(const float* __restrict__ h,
                                                      const int* __restrict__ row_ptr,
                                                      const int* __restrict__ csr_src,
                                                      const ushort* __restrict__ alpha,
                                                      const float* __restrict__ invden,
                                                      const float* __restrict__ bias,
                                                      float* __restrict__ out) {
    int lane = threadIdx.x & 63;
    int v = blockIdx.x * 4 + (threadIdx.x >> 6);
    if (v >= NN) return;
    int e_sub = lane >> 5;
    int cg = lane & 31;
    int s0 = row_ptr[v], s1 = row_ptr[v + 1];
    float4 acc = make_float4(0.f, 0.f, 0.f, 0.f);
    for (int base = s0; base < s1; base += 2) {
        int i = base + e_sub;
        if (i < s1) {
            int u = csr_src[i];
            float p = bf16_to_f(alpha[i]);
            float4 x = *(const float4*)&h[(size_t)u * OUTD + cg * 4];
            acc.x = fmaf(p, x.x, acc.x);
            acc.y = fmaf(p, x.y, acc.y);
            acc.z = fmaf(p, x.z, acc.z);
            acc.w = fmaf(p, x.w, acc.w);
        }
    }
    acc.x += __shfl_xor(acc.x, 32);
    acc.y += __shfl_xor(acc.y, 32);
    acc.z += __shfl_xor(acc.z, 32);
    acc.w += __shfl_xor(acc.w, 32);
    if (e_sub == 0) {
        float inv = invden[v];
        float4 b4 = *(const float4*)&bias[cg * 4];
        float4 o = make_float4(fmaf(acc.x, inv, b4.x), fmaf(acc.y, inv, b4.y),
                               fmaf(acc.z, inv, b4.z), fmaf(acc.w, inv, b4.w));
        *(float4*)&out[(size_t)v * OUTD + cg * 4] = o;
    }
}

// ---------------- launch ----------------

extern "C" void kernel_launch(void* const* d_in, const int* in_sizes, int n_in,
                              void* d_out, int out_size, void* d_ws, size_t ws_size,
                              hipStream_t stream) {
    const float* x     = (const float*)d_in[0];
    const int*   ei    = (const int*)d_in[1];
    const float* W1    = (const float*)d_in[2];
    const float* as1   = (const float*)d_in[3];
    const float* ad1   = (const float*)d_in[4];
    const float* b1    = (const float*)d_in[5];
    const float* W2    = (const float*)d_in[6];
    const float* as2   = (const float*)d_in[7];
    const float* ad2   = (const float*)d_in[8];
    const float* b2    = (const float*)d_in[9];
    const float* W3    = (const float*)d_in[10];
    const float* as3   = (const float*)d_in[11];
    const float* ad3   = (const float*)d_in[12];
    const float* b3    = (const float*)d_in[13];
    float* out = (float*)d_out;

    size_t off = 0;
    auto carve = [&](size_t bytes) {
        void* p = (char*)d_ws + off;
        off += (bytes + 255) & ~(size_t)255;
        return p;
    };
    int* row_ptr  = (int*)carve((NN + 1) * sizeof(int));
    int* cursor   = (int*)carve(NN * sizeof(int));
    int* csr_src  = (int*)carve(ETOT * sizeof(int));
    ushort* hb16  = (ushort*)carve((size_t)NN * HCV * sizeof(ushort)); // pre-agg h, bf16 (L1/L2)
    float* bufA   = (float*)carve((size_t)NN * OUTD * sizeof(float));  // h3 fp32 (L3)
    ushort* ghi   = (ushort*)carve((size_t)NN * HCV * sizeof(ushort)); // activations hi
    ushort* glo   = (ushort*)carve((size_t)NN * HCV * sizeof(ushort)); // activations lo
    float* als    = (float*)carve((size_t)NN * NHEADS * sizeof(float));
    float* ald    = (float*)carve((size_t)NN * NHEADS * sizeof(float));
    ushort* alphaT= (ushort*)carve((size_t)ETOT * NHEADS * sizeof(ushort)); // [ETOT][8]
    float* invden = (float*)carve((size_t)NN * NHEADS * sizeof(float));
    ushort* W1Th  = (ushort*)carve((size_t)HCV * IND * sizeof(ushort));
    ushort* W1Tl  = (ushort*)carve((size_t)HCV * IND * sizeof(ushort));
    ushort* W2Th  = (ushort*)carve((size_t)HCV * HCV * sizeof(ushort));
    ushort* W2Tl  = (ushort*)carve((size_t)HCV * HCV * sizeof(ushort));
    ushort* W3Th  = (ushort*)carve((size_t)OUTD * HCV * sizeof(ushort));
    ushort* W3Tl  = (ushort*)carve((size_t)OUTD * HCV * sizeof(ushort));
    (void)ws_size; (void)n_in; (void)in_sizes; (void)out_size;

    dim3 blk(256);

    // ---- weight prep ----
    cvt_wT<<<(IND * HCV + 255) / 256, blk, 0, stream>>>(W1, W1Th, W1Tl, IND, HCV);
    cvt_wT<<<(HCV * HCV + 255) / 256, blk, 0, stream>>>(W2, W2Th, W2Tl, HCV, HCV);
    cvt_wT<<<(HCV * OUTD + 255) / 256, blk, 0, stream>>>(W3, W3Th, W3Tl, HCV, OUTD);

    // ---- CSR build ----
    zero_i32<<<(NN + 255) / 256, blk, 0, stream>>>(cursor, NN);
    count_kernel<<<(ETOT + 255) / 256, blk, 0, stream>>>(ei, cursor);
    scan_kernel<<<1, blk, 0, stream>>>(cursor, row_ptr);
    init_cursor<<<(NN + 255) / 256, blk, 0, stream>>>(row_ptr, cursor);
    fill_kernel<<<(ETOT + 255) / 256, blk, 0, stream>>>(ei, cursor, csr_src);

    int mt = (NN + 127) / 128;
    int nwaves_nh = (NN * NHEADS + 3) / 4;
    int nwaves_n  = (NN + 3) / 4;

    // ---- layer 1 (A = fp32 x, split in-kernel; C -> bf16 hb16) ----
    gemm_mfma<<<dim3(mt, HCV / 128), blk, 0, stream>>>(x, nullptr, W1Th, W1Tl, nullptr, hb16, NN, IND, HCV);
    al_kernel<<<nwaves_nh, blk, 0, stream>>>(hb16, as1, ad1, als, ald);
    alpha_kernel<<<nwaves_n, blk, 0, stream>>>(row_ptr, csr_src, als, ald, alphaT, invden);
    gather_kernel<<<nwaves_n, blk, 0, stream>>>(hb16, row_ptr, csr_src, alphaT, invden, b1, ghi, glo);

    // ---- layer 2 ----
    gemm_mfma<<<dim3(mt, HCV / 128), blk, 0, stream>>>(ghi, glo, W2Th, W2Tl, nullptr, hb16, NN, HCV, HCV);
    al_kernel<<<nwaves_nh, blk, 0, stream>>>(hb16, as2, ad2, als, ald);
    alpha_kernel<<<nwaves_n, blk, 0, stream>>>(row_ptr, csr_src, als, ald, alphaT, invden);
    gather_kernel<<<nwaves_n, blk, 0, stream>>>(hb16, row_ptr, csr_src, alphaT, invden, b2, ghi, glo);

    // ---- layer 3 (fp32 h3 in bufA) ----
    gemm_mfma<<<dim3(mt, OUTD / 128), blk, 0, stream>>>(ghi, glo, W3Th, W3Tl, bufA, nullptr, NN, HCV, OUTD);
    al3_kernel<<<nwaves_n, blk, 0, stream>>>(bufA, as3, ad3, als, ald);
    alpha3_kernel<<<nwaves_n, blk, 0, stream>>>(row_ptr, csr_src, als, ald, alphaT, invden);
    gather3_kernel<<<nwaves_n, blk, 0, stream>>>(bufA, row_ptr, csr_src, alphaT, invden, b3, out);
}